// Round 1
// baseline (783.185 us; speedup 1.0000x reference)
//
#include <hip/hip_runtime.h>
#include <hip/hip_bf16.h>

#define EPSV 1e-5f

// ---------- CSR build ----------

__global__ void hist_kernel(const int* __restrict__ ei, int* __restrict__ cnt, int E) {
    int e = blockIdx.x * blockDim.x + threadIdx.x;
    if (e < E) atomicAdd(&cnt[ei[E + e]], 1);
}

__global__ void scanA_kernel(const int* __restrict__ cnt, int* __restrict__ rp,
                             int* __restrict__ bsum, int N) {
    __shared__ int sd[256];
    int tid = threadIdx.x;
    int base = blockIdx.x * 2048 + tid * 8;
    int v[8];
    int s = 0;
#pragma unroll
    for (int j = 0; j < 8; j++) {
        v[j] = (base + j < N) ? cnt[base + j] : 0;
        s += v[j];
    }
    sd[tid] = s;
    __syncthreads();
    for (int off = 1; off < 256; off <<= 1) {
        int t = (tid >= off) ? sd[tid - off] : 0;
        __syncthreads();
        sd[tid] += t;
        __syncthreads();
    }
    int run = sd[tid] - s;  // exclusive prefix of this thread within block
#pragma unroll
    for (int j = 0; j < 8; j++) {
        if (base + j < N) rp[base + j] = run;
        run += v[j];
    }
    if (tid == 255) bsum[blockIdx.x] = sd[255];
}

__global__ void scanB_kernel(int* bsum, int* rp, int nb, int N) {
    if (threadIdx.x == 0 && blockIdx.x == 0) {
        int run = 0;
        for (int b = 0; b < nb; b++) {
            int t = bsum[b];
            bsum[b] = run;
            run += t;
        }
        rp[N] = run;  // == E
    }
}

__global__ void scanC_kernel(int* __restrict__ rp, const int* __restrict__ bsum,
                             int* __restrict__ cursor, const int* __restrict__ cnt,
                             float* __restrict__ dinv, int N) {
    int i = blockIdx.x * blockDim.x + threadIdx.x;
    if (i < N) {
        int v = rp[i] + bsum[i >> 11];
        rp[i] = v;
        cursor[i] = v;
        dinv[i] = rsqrtf((float)cnt[i] + 1.0f);
    }
}

__global__ void scatter_kernel(const int* __restrict__ ei, int* __restrict__ cursor,
                               int* __restrict__ srcs, int E) {
    int e = blockIdx.x * blockDim.x + threadIdx.x;
    if (e < E) {
        int dst = ei[E + e];
        int pos = atomicAdd(&cursor[dst], 1);
        srcs[pos] = ei[e];
    }
}

// ---------- dense matmul H[N,64] = X[N,K] @ W[K,64] ----------
// Block 256 threads, tile BM=128 rows x BN=64 cols, BK=32.
// Thread tile 4 rows x 8 cols (32 acc regs).

template <int K>
__global__ void matmul_kernel(const float* __restrict__ X, const float* __restrict__ W,
                              float* __restrict__ H, int N) {
    const int BM = 128, BK = 32;
    __shared__ float xs[BK][BM + 4];  // transposed: xs[k][r]; stride 132 keeps b128 aligned
    __shared__ float ws[BK][64];
    int tid = threadIdx.x;
    int tx = tid & 7;   // col group: cols tx*8 .. tx*8+7
    int ty = tid >> 3;  // row group: rows ty*4 .. ty*4+3
    int row0 = blockIdx.x * BM;

    float acc[4][8];
#pragma unroll
    for (int i = 0; i < 4; i++)
#pragma unroll
        for (int j = 0; j < 8; j++) acc[i][j] = 0.f;

    for (int k0 = 0; k0 < K; k0 += BK) {
        // X tile: 128 rows x 32 k, float4 loads, stored transposed
#pragma unroll
        for (int l = 0; l < 4; l++) {
            int idx = tid + l * 256;  // 0..1023
            int r = idx >> 3;
            int kc = (idx & 7) * 4;
            float4 v = make_float4(0.f, 0.f, 0.f, 0.f);
            int grow = row0 + r;
            if (grow < N) v = *reinterpret_cast<const float4*>(&X[(size_t)grow * K + k0 + kc]);
            xs[kc + 0][r] = v.x;
            xs[kc + 1][r] = v.y;
            xs[kc + 2][r] = v.z;
            xs[kc + 3][r] = v.w;
        }
        // W tile: 32 x 64
#pragma unroll
        for (int l = 0; l < 2; l++) {
            int idx = tid + l * 256;  // 0..511
            int kk = idx >> 4;
            int f = (idx & 15) * 4;
            *reinterpret_cast<float4*>(&ws[kk][f]) =
                *reinterpret_cast<const float4*>(&W[(k0 + kk) * 64 + f]);
        }
        __syncthreads();
#pragma unroll
        for (int kk = 0; kk < BK; kk++) {
            float4 xv = *reinterpret_cast<const float4*>(&xs[kk][ty * 4]);
            float4 w0 = *reinterpret_cast<const float4*>(&ws[kk][tx * 8]);
            float4 w1 = *reinterpret_cast<const float4*>(&ws[kk][tx * 8 + 4]);
            float xr[4] = {xv.x, xv.y, xv.z, xv.w};
            float wf[8] = {w0.x, w0.y, w0.z, w0.w, w1.x, w1.y, w1.z, w1.w};
#pragma unroll
            for (int i = 0; i < 4; i++)
#pragma unroll
                for (int j = 0; j < 8; j++) acc[i][j] += xr[i] * wf[j];
        }
        __syncthreads();
    }
#pragma unroll
    for (int i = 0; i < 4; i++) {
        int r = row0 + ty * 4 + i;
        if (r < N) {
#pragma unroll
            for (int j = 0; j < 8; j += 4) {
                float4 o = make_float4(acc[i][j], acc[i][j + 1], acc[i][j + 2], acc[i][j + 3]);
                *reinterpret_cast<float4*>(&H[(size_t)r * 64 + tx * 8 + j]) = o;
            }
        }
    }
}

// ---------- edge aggregation: one wave per node, lane = feature ----------
// out[i] = relu( dinv[i] * sum_e dinv[src_e]*H[src_e] + dinv[i]^2 * H[i] + b )

__global__ void agg_kernel(const float* __restrict__ H, const int* __restrict__ rp,
                           const int* __restrict__ srcs, const float* __restrict__ dinv,
                           const float* __restrict__ bias, float* __restrict__ out, int N) {
    int wave = (blockIdx.x * blockDim.x + threadIdx.x) >> 6;
    int lane = threadIdx.x & 63;
    if (wave >= N) return;
    int beg = rp[wave], end = rp[wave + 1];
    float di = dinv[wave];
    float acc = 0.f;
    for (int e = beg; e < end; e++) {
        int s = srcs[e];
        acc += dinv[s] * H[(size_t)s * 64 + lane];
    }
    float v = di * acc + di * di * H[(size_t)wave * 64 + lane] + bias[lane];
    out[(size_t)wave * 64 + lane] = fmaxf(v, 0.f);
}

// ---------- per-feature column sums (GraphNorm stats) ----------

__global__ void colstats_kernel(const float* __restrict__ A, float* __restrict__ sums, int N) {
    __shared__ float ls[256], ls2[256];
    int tid = threadIdx.x;
    int f = tid & 63;
    float s = 0.f, s2 = 0.f;
    for (int r = blockIdx.x * 4 + (tid >> 6); r < N; r += gridDim.x * 4) {
        float v = A[(size_t)r * 64 + f];
        s += v;
        s2 += v * v;
    }
    ls[tid] = s;
    ls2[tid] = s2;
    __syncthreads();
    if (tid < 64) {
        s = ls[tid] + ls[tid + 64] + ls[tid + 128] + ls[tid + 192];
        s2 = ls2[tid] + ls2[tid + 64] + ls2[tid + 128] + ls2[tid + 192];
        atomicAdd(&sums[f], s);
        atomicAdd(&sums[64 + f], s2);
    }
}

// ---------- GraphNorm-apply + LayerNorm fused (wave per node) ----------

__device__ __forceinline__ float gn_ln_row(float x, float mean, float var, float ms, float gw,
                                           float gb, float lw, float lb) {
    float g = gw * (x - ms * mean) * rsqrtf(var + EPSV) + gb;
    float mu = g;
#pragma unroll
    for (int off = 32; off; off >>= 1) mu += __shfl_xor(mu, off);
    mu *= (1.f / 64.f);
    float c = g - mu;
    float vv = c * c;
#pragma unroll
    for (int off = 32; off; off >>= 1) vv += __shfl_xor(vv, off);
    vv *= (1.f / 64.f);
    return lw * c * rsqrtf(vv + EPSV) + lb;
}

__global__ void gnln_kernel(const float* __restrict__ A, const float* __restrict__ sums,
                            const float* __restrict__ gn_w, const float* __restrict__ gn_b,
                            const float* __restrict__ gn_ms, const float* __restrict__ ln_w,
                            const float* __restrict__ ln_b, float* __restrict__ out, int N) {
    int wave = (blockIdx.x * blockDim.x + threadIdx.x) >> 6;
    int lane = threadIdx.x & 63;
    if (wave >= N) return;
    float invN = 1.0f / (float)N;
    float mean = sums[lane] * invN;
    float m2 = sums[64 + lane] * invN;
    float ms = gn_ms[lane];
    float var = m2 - 2.f * ms * mean * mean + ms * ms * mean * mean;
    float y = gn_ln_row(A[(size_t)wave * 64 + lane], mean, var, ms, gn_w[lane], gn_b[lane],
                        ln_w[lane], ln_b[lane]);
    out[(size_t)wave * 64 + lane] = y;
}

// ---------- layer-2 norms fused with max-pool (no h2 writeback) ----------

__device__ __forceinline__ unsigned fkey(float f) {
    unsigned u = __float_as_uint(f);
    return (u & 0x80000000u) ? ~u : (u | 0x80000000u);
}

__global__ void gnlnmax_kernel(const float* __restrict__ A, const float* __restrict__ sums,
                               const float* __restrict__ gn_w, const float* __restrict__ gn_b,
                               const float* __restrict__ gn_ms, const float* __restrict__ ln_w,
                               const float* __restrict__ ln_b, unsigned* __restrict__ pooled,
                               int N) {
    __shared__ float lmax[256];
    int lane = threadIdx.x & 63;
    int wave0 = (blockIdx.x * blockDim.x + threadIdx.x) >> 6;
    int nw = (gridDim.x * blockDim.x) >> 6;
    float invN = 1.0f / (float)N;
    float mean = sums[lane] * invN;
    float m2 = sums[64 + lane] * invN;
    float ms = gn_ms[lane];
    float var = m2 - 2.f * ms * mean * mean + ms * ms * mean * mean;
    float gw = gn_w[lane], gb = gn_b[lane], lw = ln_w[lane], lb = ln_b[lane];
    float mx = -3.4e38f;
    for (int i = wave0; i < N; i += nw) {
        float y = gn_ln_row(A[(size_t)i * 64 + lane], mean, var, ms, gw, gb, lw, lb);
        mx = fmaxf(mx, y);
    }
    lmax[threadIdx.x] = mx;
    __syncthreads();
    if (threadIdx.x < 64) {
        float m = fmaxf(fmaxf(lmax[threadIdx.x], lmax[threadIdx.x + 64]),
                        fmaxf(lmax[threadIdx.x + 128], lmax[threadIdx.x + 192]));
        atomicMax(&pooled[threadIdx.x], fkey(m));
    }
}

// ---------- final FC: out[32] = pooled[64] @ fc_W[64,32] + fc_b ----------

__global__ void final_kernel(const unsigned* __restrict__ pooled, const float* __restrict__ fc_W,
                             const float* __restrict__ fc_b, float* __restrict__ out) {
    __shared__ float p[64];
    int t = threadIdx.x;
    if (t < 64) {
        unsigned u = pooled[t];
        p[t] = (u & 0x80000000u) ? __uint_as_float(u ^ 0x80000000u) : __uint_as_float(~u);
    }
    __syncthreads();
    if (t < 32) {
        float acc = fc_b[t];
#pragma unroll
        for (int f = 0; f < 64; f++) acc += p[f] * fc_W[f * 32 + t];
        out[t] = acc;
    }
}

// ---------- launch ----------

static inline size_t align_up(size_t v, size_t a) { return (v + a - 1) & ~(a - 1); }

extern "C" void kernel_launch(void* const* d_in, const int* in_sizes, int n_in, void* d_out,
                              int out_size, void* d_ws, size_t ws_size, hipStream_t stream) {
    const float* x = (const float*)d_in[0];
    const int* ei = (const int*)d_in[1];
    const float* W1 = (const float*)d_in[2];
    const float* b1 = (const float*)d_in[3];
    const float* W2 = (const float*)d_in[4];
    const float* b2 = (const float*)d_in[5];
    const float* gn_w = (const float*)d_in[6];
    const float* gn_b = (const float*)d_in[7];
    const float* gn_ms = (const float*)d_in[8];
    const float* ln_w = (const float*)d_in[9];
    const float* ln_b = (const float*)d_in[10];
    const float* fc_W = (const float*)d_in[11];
    const float* fc_b = (const float*)d_in[12];
    float* out = (float*)d_out;

    const int N = in_sizes[0] / 128;
    const int E = in_sizes[1] / 2;

    char* ws = (char*)d_ws;
    size_t off = 0;
    auto alloc = [&](size_t bytes) {
        char* p = ws + off;
        off = align_up(off + bytes, 256);
        return p;
    };
    int* cnt = (int*)alloc((size_t)N * 4);
    int* rp = (int*)alloc((size_t)(N + 1) * 4);
    int* cursor = (int*)alloc((size_t)N * 4);
    int* bsum = (int*)alloc(256 * 4);
    float* dinv = (float*)alloc((size_t)N * 4);
    int* srcs = (int*)alloc((size_t)E * 4);
    float* bufA = (float*)alloc((size_t)N * 64 * 4);
    float* bufB = (float*)alloc((size_t)N * 64 * 4);
    float* sums = (float*)alloc(256 * 4);  // [0:128) layer1, [128:256) layer2
    unsigned* pooled = (unsigned*)alloc(64 * 4);

    hipMemsetAsync(cnt, 0, (size_t)N * 4, stream);
    hipMemsetAsync(sums, 0, 256 * 4, stream);
    hipMemsetAsync(pooled, 0, 64 * 4, stream);

    // CSR build
    int nbE = (E + 255) / 256;
    int nbScan = (N + 2047) / 2048;
    hist_kernel<<<nbE, 256, 0, stream>>>(ei, cnt, E);
    scanA_kernel<<<nbScan, 256, 0, stream>>>(cnt, rp, bsum, N);
    scanB_kernel<<<1, 1, 0, stream>>>(bsum, rp, nbScan, N);
    scanC_kernel<<<(N + 255) / 256, 256, 0, stream>>>(rp, bsum, cursor, cnt, dinv, N);
    scatter_kernel<<<nbE, 256, 0, stream>>>(ei, cursor, srcs, E);

    int nbMM = (N + 127) / 128;
    int nbWave = (N + 3) / 4;  // 4 waves (nodes) per 256-thread block

    // Layer 1
    matmul_kernel<128><<<nbMM, 256, 0, stream>>>(x, W1, bufA, N);
    agg_kernel<<<nbWave, 256, 0, stream>>>(bufA, rp, srcs, dinv, b1, bufB, N);
    colstats_kernel<<<256, 256, 0, stream>>>(bufB, sums, N);
    gnln_kernel<<<nbWave, 256, 0, stream>>>(bufB, sums, gn_w, gn_b, gn_ms, ln_w, ln_b, bufA, N);

    // Layer 2
    matmul_kernel<64><<<nbMM, 256, 0, stream>>>(bufA, W2, bufB, N);
    agg_kernel<<<nbWave, 256, 0, stream>>>(bufB, rp, srcs, dinv, b2, bufA, N);
    colstats_kernel<<<256, 256, 0, stream>>>(bufA, sums + 128, N);
    gnlnmax_kernel<<<512, 256, 0, stream>>>(bufA, sums + 128, gn_w, gn_b, gn_ms, ln_w, ln_b,
                                            pooled, N);

    final_kernel<<<1, 64, 0, stream>>>(pooled, fc_W, fc_b, out);
}

// Round 2
// 590.595 us; speedup vs baseline: 1.3261x; 1.3261x over previous
//
#include <hip/hip_runtime.h>
#include <hip/hip_bf16.h>

#define EPSV 1e-5f

typedef __attribute__((ext_vector_type(8))) short bf16x8;
typedef __attribute__((ext_vector_type(4))) float f32x4;

__device__ __forceinline__ ushort f2bf(float f) {
    union { float f; unsigned u; } c; c.f = f;
    unsigned u = c.u;
    return (ushort)((u + 0x7fffu + ((u >> 16) & 1u)) >> 16);
}
__device__ __forceinline__ float bf2f(ushort h) {
    union { unsigned u; float f; } c; c.u = ((unsigned)h) << 16;
    return c.f;
}

// ---------- CSR build ----------

__global__ void hist_kernel(const int* __restrict__ ei, int* __restrict__ cnt, int E) {
    int e = blockIdx.x * blockDim.x + threadIdx.x;
    if (e < E) atomicAdd(&cnt[ei[E + e]], 1);
}

__global__ void scanA_kernel(const int* __restrict__ cnt, int* __restrict__ rp,
                             int* __restrict__ bsum, int N) {
    __shared__ int sd[256];
    int tid = threadIdx.x;
    int base = blockIdx.x * 2048 + tid * 8;
    int v[8];
    int s = 0;
#pragma unroll
    for (int j = 0; j < 8; j++) {
        v[j] = (base + j < N) ? cnt[base + j] : 0;
        s += v[j];
    }
    sd[tid] = s;
    __syncthreads();
    for (int off = 1; off < 256; off <<= 1) {
        int t = (tid >= off) ? sd[tid - off] : 0;
        __syncthreads();
        sd[tid] += t;
        __syncthreads();
    }
    int run = sd[tid] - s;
#pragma unroll
    for (int j = 0; j < 8; j++) {
        if (base + j < N) rp[base + j] = run;
        run += v[j];
    }
    if (tid == 255) bsum[blockIdx.x] = sd[255];
}

// one-wave shuffle scan (nb <= 64 for N=100k)
__global__ void scanB_kernel(int* bsum, int* rp, int nb, int N) {
    int lane = threadIdx.x;
    if (nb <= 64) {
        int v = (lane < nb) ? bsum[lane] : 0;
        int orig = v;
#pragma unroll
        for (int off = 1; off < 64; off <<= 1) {
            int t = __shfl_up(v, off);
            if (lane >= off) v += t;
        }
        if (lane < nb) bsum[lane] = v - orig;
        if (lane == 63) rp[N] = v;
    } else if (lane == 0) {
        int run = 0;
        for (int b = 0; b < nb; b++) {
            int t = bsum[b];
            bsum[b] = run;
            run += t;
        }
        rp[N] = run;
    }
}

__global__ void scanC_kernel(int* __restrict__ rp, const int* __restrict__ bsum,
                             int* __restrict__ cursor, const int* __restrict__ cnt,
                             float* __restrict__ dinv, int N) {
    int i = blockIdx.x * blockDim.x + threadIdx.x;
    if (i < N) {
        int v = rp[i] + bsum[i >> 11];
        rp[i] = v;
        cursor[i] = v;
        dinv[i] = rsqrtf((float)cnt[i] + 1.0f);
    }
}

__global__ void scatter_kernel(const int* __restrict__ ei, int* __restrict__ cursor,
                               int* __restrict__ srcs, int E) {
    int e = blockIdx.x * blockDim.x + threadIdx.x;
    if (e < E) {
        int dst = ei[E + e];
        int pos = atomicAdd(&cursor[dst], 1);
        srcs[pos] = ei[e];
    }
}

// ---------- W pre-swizzle into MFMA B-fragment order ----------
// element (k,n) -> wsw[((k>>3)*64 + n)*8 + (k&7)]  (bf16)

__global__ void prep_w(const float* __restrict__ W1, const float* __restrict__ W2,
                       ushort* __restrict__ wsw1, ushort* __restrict__ wsw2) {
    int t = blockIdx.x * blockDim.x + threadIdx.x;
    if (t < 128 * 64) {
        int k = t >> 6, n = t & 63;
        wsw1[((k >> 3) * 64 + n) * 8 + (k & 7)] = f2bf(W1[t]);
    }
    if (t < 64 * 64) {
        int k = t >> 6, n = t & 63;
        wsw2[((k >> 3) * 64 + n) * 8 + (k & 7)] = f2bf(W2[t]);
    }
}

// ---------- matmul1: Ht[N,64](bf16) = dinv[r] * (X[N,128](fp32) @ W1) ----------
// block 256 = 4 waves; wave w owns rows blk*64 + w*16 + m (m=lane&15), all 4 col-tiles.
// MFMA 16x16x32 bf16: A frag a[j]=A[m][q*8+j], B frag b[j]=B[q*8+j][n], D: col=lane&15,row=q*4+reg.

__global__ void __launch_bounds__(256) mm1_kernel(const float* __restrict__ X,
                                                  const ushort* __restrict__ wsw,
                                                  const float* __restrict__ dinv,
                                                  ushort* __restrict__ Ht, int N) {
    const int KO = 4;  // K=128
    int w = threadIdx.x >> 6, lane = threadIdx.x & 63;
    int m = lane & 15, q = lane >> 4;
    int row = blockIdx.x * 64 + w * 16 + m;

    bf16x8 afrag[KO];
#pragma unroll
    for (int kk = 0; kk < KO; kk++) {
        float xv[8];
        if (row < N) {
            const float4* xp = reinterpret_cast<const float4*>(X + (size_t)row * 128 + kk * 32 + q * 8);
            float4 v0 = xp[0], v1 = xp[1];
            xv[0] = v0.x; xv[1] = v0.y; xv[2] = v0.z; xv[3] = v0.w;
            xv[4] = v1.x; xv[5] = v1.y; xv[6] = v1.z; xv[7] = v1.w;
        } else {
#pragma unroll
            for (int j = 0; j < 8; j++) xv[j] = 0.f;
        }
#pragma unroll
        for (int j = 0; j < 8; j++) afrag[kk][j] = (short)f2bf(xv[j]);
    }

    float dv[4];
#pragma unroll
    for (int reg = 0; reg < 4; reg++) {
        int r = blockIdx.x * 64 + w * 16 + q * 4 + reg;
        dv[reg] = (r < N) ? dinv[r] : 0.f;
    }

    const bf16x8* wp = reinterpret_cast<const bf16x8*>(wsw);
#pragma unroll
    for (int ct = 0; ct < 4; ct++) {
        f32x4 acc = {0.f, 0.f, 0.f, 0.f};
#pragma unroll
        for (int kk = 0; kk < KO; kk++) {
            bf16x8 b = wp[(kk * 4 + q) * 64 + ct * 16 + m];
            acc = __builtin_amdgcn_mfma_f32_16x16x32_bf16(afrag[kk], b, acc, 0, 0, 0);
        }
#pragma unroll
        for (int reg = 0; reg < 4; reg++) {
            int r = blockIdx.x * 64 + w * 16 + q * 4 + reg;
            if (r < N) Ht[(size_t)r * 64 + ct * 16 + m] = f2bf(acc[reg] * dv[reg]);
        }
    }
}

// ---------- matmul2: fused GraphNorm+LayerNorm on A, then Ht2 = dinv * (norm(A) @ W2) ----------

__global__ void __launch_bounds__(256) mm2_kernel(
    const ushort* __restrict__ A2, const ushort* __restrict__ wsw,
    const float* __restrict__ sums, const float* __restrict__ gn_w,
    const float* __restrict__ gn_b, const float* __restrict__ gn_ms,
    const float* __restrict__ ln_w, const float* __restrict__ ln_b,
    const float* __restrict__ dinv, ushort* __restrict__ Ht, int N) {
    __shared__ float sg[64], tg[64], lwv[64], lbv[64];
    int t = threadIdx.x;
    if (t < 64) {
        float invN = 1.0f / (float)N;
        float mean = sums[t] * invN;
        float m2 = sums[64 + t] * invN;
        float ms = gn_ms[t];
        float var = m2 - 2.f * ms * mean * mean + ms * ms * mean * mean;
        float s = gn_w[t] * rsqrtf(var + EPSV);
        sg[t] = s;
        tg[t] = gn_b[t] - s * ms * mean;
        lwv[t] = ln_w[t];
        lbv[t] = ln_b[t];
    }
    __syncthreads();

    int w = t >> 6, lane = t & 63;
    int m = lane & 15, q = lane >> 4;
    int row = blockIdx.x * 64 + w * 16 + m;

    // load 16 features (2 k-octets), apply GraphNorm
    float g[16];
#pragma unroll
    for (int kk = 0; kk < 2; kk++) {
        uint4 u = make_uint4(0, 0, 0, 0);
        if (row < N)
            u = *reinterpret_cast<const uint4*>(A2 + (size_t)row * 64 + kk * 32 + q * 8);
        unsigned uu[4] = {u.x, u.y, u.z, u.w};
#pragma unroll
        for (int p = 0; p < 4; p++) {
            int f0 = kk * 32 + q * 8 + 2 * p;
            g[kk * 8 + 2 * p] = sg[f0] * bf2f((ushort)uu[p]) + tg[f0];
            g[kk * 8 + 2 * p + 1] = sg[f0 + 1] * bf2f((ushort)(uu[p] >> 16)) + tg[f0 + 1];
        }
    }
    // LayerNorm over the row (4 q-lanes hold disjoint 16 features each)
    float s1 = 0.f;
#pragma unroll
    for (int i = 0; i < 16; i++) s1 += g[i];
    s1 += __shfl_xor(s1, 16);
    s1 += __shfl_xor(s1, 32);
    float mu = s1 * (1.f / 64.f);
    float s2 = 0.f;
#pragma unroll
    for (int i = 0; i < 16; i++) {
        float c = g[i] - mu;
        s2 += c * c;
    }
    s2 += __shfl_xor(s2, 16);
    s2 += __shfl_xor(s2, 32);
    float rs = rsqrtf(s2 * (1.f / 64.f) + EPSV);

    bf16x8 afrag[2];
#pragma unroll
    for (int kk = 0; kk < 2; kk++) {
#pragma unroll
        for (int j = 0; j < 8; j++) {
            int f = kk * 32 + q * 8 + j;
            float y = lwv[f] * (g[kk * 8 + j] - mu) * rs + lbv[f];
            afrag[kk][j] = (short)f2bf(y);
        }
    }

    float dv[4];
#pragma unroll
    for (int reg = 0; reg < 4; reg++) {
        int r = blockIdx.x * 64 + w * 16 + q * 4 + reg;
        dv[reg] = (r < N) ? dinv[r] : 0.f;
    }

    const bf16x8* wp = reinterpret_cast<const bf16x8*>(wsw);
#pragma unroll
    for (int ct = 0; ct < 4; ct++) {
        f32x4 acc = {0.f, 0.f, 0.f, 0.f};
#pragma unroll
        for (int kk = 0; kk < 2; kk++) {
            bf16x8 b = wp[(kk * 4 + q) * 64 + ct * 16 + m];
            acc = __builtin_amdgcn_mfma_f32_16x16x32_bf16(afrag[kk], b, acc, 0, 0, 0);
        }
#pragma unroll
        for (int reg = 0; reg < 4; reg++) {
            int r = blockIdx.x * 64 + w * 16 + q * 4 + reg;
            if (r < N) Ht[(size_t)r * 64 + ct * 16 + m] = f2bf(acc[reg] * dv[reg]);
        }
    }
}

// ---------- edge aggregation (bf16 gather, 2 edges/wave-iter, fused column stats) ----------
// out[i] = relu( di * sum_e Ht[src_e] + di*Ht[i] + b ),  Ht = dinv*h  (bf16)

__global__ void __launch_bounds__(256) agg_kernel(
    const ushort* __restrict__ Ht, const int* __restrict__ rp, const int* __restrict__ srcs,
    const float* __restrict__ dinv, const float* __restrict__ bias,
    ushort* __restrict__ out, float* __restrict__ sums, int N) {
    int gw = (blockIdx.x * blockDim.x + threadIdx.x) >> 6;
    int nw = (gridDim.x * blockDim.x) >> 6;
    int lane = threadIdx.x & 63, half = lane >> 5, fl = lane & 31;
    const unsigned* H32 = reinterpret_cast<const unsigned*>(Ht);
    unsigned* out32 = reinterpret_cast<unsigned*>(out);
    float bx = bias[2 * fl], by = bias[2 * fl + 1];
    float ps1x = 0.f, ps1y = 0.f, ps2x = 0.f, ps2y = 0.f;

    for (int i = gw; i < N; i += nw) {
        int beg = rp[i], end = rp[i + 1];
        float di = dinv[i];
        float ax0 = 0.f, ay0 = 0.f, ax1 = 0.f, ay1 = 0.f;
        int e = beg + half;
        for (; e + 2 < end; e += 4) {
            int s0 = srcs[e], s1 = srcs[e + 2];
            unsigned u0 = H32[(size_t)s0 * 32 + fl];
            unsigned u1 = H32[(size_t)s1 * 32 + fl];
            ax0 += bf2f((ushort)u0); ay0 += bf2f((ushort)(u0 >> 16));
            ax1 += bf2f((ushort)u1); ay1 += bf2f((ushort)(u1 >> 16));
        }
        if (e < end) {
            unsigned u = H32[(size_t)srcs[e] * 32 + fl];
            ax0 += bf2f((ushort)u); ay0 += bf2f((ushort)(u >> 16));
        }
        float ax = ax0 + ax1, ay = ay0 + ay1;
        ax += __shfl_xor(ax, 32);
        ay += __shfl_xor(ay, 32);
        unsigned us = H32[(size_t)i * 32 + fl];
        float vx = fmaxf(di * ax + di * bf2f((ushort)us) + bx, 0.f);
        float vy = fmaxf(di * ay + di * bf2f((ushort)(us >> 16)) + by, 0.f);
        if (half == 0) {
            out32[(size_t)i * 32 + fl] = (unsigned)f2bf(vx) | ((unsigned)f2bf(vy) << 16);
            ps1x += vx; ps1y += vy;
            ps2x += vx * vx; ps2y += vy * vy;
        }
    }

    __shared__ float red[4][32][4];
    int wv = threadIdx.x >> 6;
    if (half == 0) {
        red[wv][fl][0] = ps1x; red[wv][fl][1] = ps1y;
        red[wv][fl][2] = ps2x; red[wv][fl][3] = ps2y;
    }
    __syncthreads();
    if (threadIdx.x < 128) {
        int f2 = threadIdx.x >> 2, c = threadIdx.x & 3;
        float v = red[0][f2][c] + red[1][f2][c] + red[2][f2][c] + red[3][f2][c];
        int f = 2 * f2 + (c & 1);
        atomicAdd(&sums[(c >> 1) * 64 + f], v);
    }
}

// ---------- layer-2 norms + max-pool (bf16 input) ----------

__device__ __forceinline__ float gn_ln_row(float x, float mean, float var, float ms, float gw,
                                           float gb, float lw, float lb) {
    float g = gw * (x - ms * mean) * rsqrtf(var + EPSV) + gb;
    float mu = g;
#pragma unroll
    for (int off = 32; off; off >>= 1) mu += __shfl_xor(mu, off);
    mu *= (1.f / 64.f);
    float c = g - mu;
    float vv = c * c;
#pragma unroll
    for (int off = 32; off; off >>= 1) vv += __shfl_xor(vv, off);
    vv *= (1.f / 64.f);
    return lw * c * rsqrtf(vv + EPSV) + lb;
}

__device__ __forceinline__ unsigned fkey(float f) {
    unsigned u = __float_as_uint(f);
    return (u & 0x80000000u) ? ~u : (u | 0x80000000u);
}

__global__ void gnlnmax_kernel(const ushort* __restrict__ A, const float* __restrict__ sums,
                               const float* __restrict__ gn_w, const float* __restrict__ gn_b,
                               const float* __restrict__ gn_ms, const float* __restrict__ ln_w,
                               const float* __restrict__ ln_b, unsigned* __restrict__ pooled,
                               int N) {
    __shared__ float lmax[256];
    int lane = threadIdx.x & 63;
    int wave0 = (blockIdx.x * blockDim.x + threadIdx.x) >> 6;
    int nw = (gridDim.x * blockDim.x) >> 6;
    float invN = 1.0f / (float)N;
    float mean = sums[lane] * invN;
    float m2 = sums[64 + lane] * invN;
    float ms = gn_ms[lane];
    float var = m2 - 2.f * ms * mean * mean + ms * ms * mean * mean;
    float gw = gn_w[lane], gb = gn_b[lane], lw = ln_w[lane], lb = ln_b[lane];
    float mx = -3.4e38f;
    for (int i = wave0; i < N; i += nw) {
        float y = gn_ln_row(bf2f(A[(size_t)i * 64 + lane]), mean, var, ms, gw, gb, lw, lb);
        mx = fmaxf(mx, y);
    }
    lmax[threadIdx.x] = mx;
    __syncthreads();
    if (threadIdx.x < 64) {
        float m = fmaxf(fmaxf(lmax[threadIdx.x], lmax[threadIdx.x + 64]),
                        fmaxf(lmax[threadIdx.x + 128], lmax[threadIdx.x + 192]));
        atomicMax(&pooled[threadIdx.x], fkey(m));
    }
}

// ---------- final FC ----------

__global__ void final_kernel(const unsigned* __restrict__ pooled, const float* __restrict__ fc_W,
                             const float* __restrict__ fc_b, float* __restrict__ out) {
    __shared__ float p[64];
    int t = threadIdx.x;
    if (t < 64) {
        unsigned u = pooled[t];
        p[t] = (u & 0x80000000u) ? __uint_as_float(u ^ 0x80000000u) : __uint_as_float(~u);
    }
    __syncthreads();
    if (t < 32) {
        float acc = fc_b[t];
#pragma unroll
        for (int f = 0; f < 64; f++) acc += p[f] * fc_W[f * 32 + t];
        out[t] = acc;
    }
}

// ---------- launch ----------

static inline size_t align_up(size_t v, size_t a) { return (v + a - 1) & ~(a - 1); }

extern "C" void kernel_launch(void* const* d_in, const int* in_sizes, int n_in, void* d_out,
                              int out_size, void* d_ws, size_t ws_size, hipStream_t stream) {
    const float* x = (const float*)d_in[0];
    const int* ei = (const int*)d_in[1];
    const float* W1 = (const float*)d_in[2];
    const float* b1 = (const float*)d_in[3];
    const float* W2 = (const float*)d_in[4];
    const float* b2 = (const float*)d_in[5];
    const float* gn_w = (const float*)d_in[6];
    const float* gn_b = (const float*)d_in[7];
    const float* gn_ms = (const float*)d_in[8];
    const float* ln_w = (const float*)d_in[9];
    const float* ln_b = (const float*)d_in[10];
    const float* fc_W = (const float*)d_in[11];
    const float* fc_b = (const float*)d_in[12];
    float* out = (float*)d_out;

    const int N = in_sizes[0] / 128;
    const int E = in_sizes[1] / 2;

    char* ws = (char*)d_ws;
    size_t off = 0;
    auto alloc = [&](size_t bytes) {
        char* p = ws + off;
        off = align_up(off + bytes, 256);
        return p;
    };
    int* cnt = (int*)alloc((size_t)N * 4);
    int* rp = (int*)alloc((size_t)(N + 1) * 4);
    int* cursor = (int*)alloc((size_t)N * 4);
    int* bsum = (int*)alloc(256 * 4);
    float* dinv = (float*)alloc((size_t)N * 4);
    int* srcs = (int*)alloc((size_t)E * 4);
    ushort* bufA = (ushort*)alloc((size_t)N * 64 * 2);  // matmul outputs (Ht1 then Ht2)
    ushort* bufB = (ushort*)alloc((size_t)N * 64 * 2);  // agg outputs
    ushort* wsw1 = (ushort*)alloc(128 * 64 * 2);
    ushort* wsw2 = (ushort*)alloc(64 * 64 * 2);
    float* sums = (float*)alloc(256 * 4);  // [0:128) layer1, [128:256) layer2
    unsigned* pooled = (unsigned*)alloc(64 * 4);

    hipMemsetAsync(cnt, 0, (size_t)N * 4, stream);
    hipMemsetAsync(sums, 0, 256 * 4, stream);
    hipMemsetAsync(pooled, 0, 64 * 4, stream);

    // CSR build
    int nbE = (E + 255) / 256;
    int nbScan = (N + 2047) / 2048;
    prep_w<<<32, 256, 0, stream>>>(W1, W2, wsw1, wsw2);
    hist_kernel<<<nbE, 256, 0, stream>>>(ei, cnt, E);
    scanA_kernel<<<nbScan, 256, 0, stream>>>(cnt, rp, bsum, N);
    scanB_kernel<<<1, 64, 0, stream>>>(bsum, rp, nbScan, N);
    scanC_kernel<<<(N + 255) / 256, 256, 0, stream>>>(rp, bsum, cursor, cnt, dinv, N);
    scatter_kernel<<<nbE, 256, 0, stream>>>(ei, cursor, srcs, E);

    int nbMM = (N + 63) / 64;

    // Layer 1
    mm1_kernel<<<nbMM, 256, 0, stream>>>(x, wsw1, dinv, bufA, N);
    agg_kernel<<<2048, 256, 0, stream>>>(bufA, rp, srcs, dinv, b1, bufB, sums, N);

    // Layer 2 (gn+ln fused into matmul2's A load; colstats fused into agg)
    mm2_kernel<<<nbMM, 256, 0, stream>>>(bufB, wsw2, sums, gn_w, gn_b, gn_ms, ln_w, ln_b, dinv,
                                         bufA, N);
    agg_kernel<<<2048, 256, 0, stream>>>(bufA, rp, srcs, dinv, b2, bufB, sums + 128, N);
    gnlnmax_kernel<<<512, 256, 0, stream>>>(bufB, sums + 128, gn_w, gn_b, gn_ms, ln_w, ln_b,
                                            pooled, N);

    final_kernel<<<1, 64, 0, stream>>>(pooled, fc_W, fc_b, out);
}

// Round 3
// 446.195 us; speedup vs baseline: 1.7553x; 1.3236x over previous
//
#include <hip/hip_runtime.h>
#include <hip/hip_bf16.h>

#define EPSV 1e-5f
#define CHUNK 256   // dst nodes per bucket (bucket = dst >> 8)
#define MAXNB 512   // supports N <= 131072

typedef __attribute__((ext_vector_type(8))) short bf16x8;
typedef __attribute__((ext_vector_type(4))) float f32x4;

__device__ __forceinline__ ushort f2bf(float f) {
    union { float f; unsigned u; } c; c.f = f;
    unsigned u = c.u;
    return (ushort)((u + 0x7fffu + ((u >> 16) & 1u)) >> 16);
}
__device__ __forceinline__ float bf2f(ushort h) {
    union { unsigned u; float f; } c; c.u = ((unsigned)h) << 16;
    return c.f;
}

// ---------- bucketed CSR build ----------
// pack: low 20 bits = src (N < 2^20), bits 20..27 = dst & 255

__global__ void bucket_hist(const int* __restrict__ ei, int* __restrict__ bcnt, int E, int NB) {
    __shared__ int h[MAXNB];
    for (int b = threadIdx.x; b < NB; b += 256) h[b] = 0;
    __syncthreads();
    int stride = gridDim.x * 256;
    for (int e = blockIdx.x * 256 + threadIdx.x; e < E; e += stride)
        atomicAdd(&h[ei[E + e] >> 8], 1);
    __syncthreads();
    for (int b = threadIdx.x; b < NB; b += 256)
        if (h[b]) atomicAdd(&bcnt[b], h[b]);
}

__global__ void bucket_scan(const int* __restrict__ bcnt, int* __restrict__ bbase,
                            int* __restrict__ bcur, int NB) {
    __shared__ int sd[MAXNB];
    int t = threadIdx.x;
    int v = (t < NB) ? bcnt[t] : 0;
    sd[t] = v;
    __syncthreads();
    for (int off = 1; off < MAXNB; off <<= 1) {
        int x = (t >= off) ? sd[t - off] : 0;
        __syncthreads();
        sd[t] += x;
        __syncthreads();
    }
    int excl = sd[t] - v;
    if (t < NB) { bbase[t] = excl; bcur[t] = excl; }
    if (t == MAXNB - 1) bbase[NB] = sd[MAXNB - 1];
}

#define EPB 8192  // edges per bucket_scatter block

__global__ void __launch_bounds__(256) bucket_scatter(const int* __restrict__ ei,
                                                      int* __restrict__ bcur,
                                                      unsigned* __restrict__ bdata, int E,
                                                      int NB) {
    __shared__ int h[MAXNB];
    __shared__ int cur[MAXNB];
    int base = blockIdx.x * EPB;
    int end = min(base + EPB, E);
    for (int b = threadIdx.x; b < NB; b += 256) h[b] = 0;
    __syncthreads();
    for (int e = base + threadIdx.x; e < end; e += 256)
        atomicAdd(&h[ei[E + e] >> 8], 1);
    __syncthreads();
    for (int b = threadIdx.x; b < NB; b += 256) {
        int c = h[b];
        cur[b] = c ? atomicAdd(&bcur[b], c) : 0;
    }
    __syncthreads();
    for (int e = base + threadIdx.x; e < end; e += 256) {
        int s = ei[e], d = ei[E + e];
        int pos = atomicAdd(&cur[d >> 8], 1);
        bdata[pos] = (unsigned)s | ((unsigned)(d & (CHUNK - 1)) << 20);
    }
}

__global__ void fine_hist(const unsigned* __restrict__ bdata, const int* __restrict__ bbase,
                          int* __restrict__ cnt, int N) {
    __shared__ int h[CHUNK];
    h[threadIdx.x] = 0;
    __syncthreads();
    int beg = bbase[blockIdx.x], end = bbase[blockIdx.x + 1];
    for (int e = beg + threadIdx.x; e < end; e += 256)
        atomicAdd(&h[bdata[e] >> 20], 1);
    __syncthreads();
    int node = blockIdx.x * CHUNK + threadIdx.x;
    if (node < N) cnt[node] = h[threadIdx.x];
}

__global__ void fine_scatter(const unsigned* __restrict__ bdata, const int* __restrict__ bbase,
                             const int* __restrict__ rp, int* __restrict__ srcs, int N) {
    __shared__ int cur[CHUNK];
    int node = blockIdx.x * CHUNK + threadIdx.x;
    cur[threadIdx.x] = (node < N) ? rp[node] : 0;
    __syncthreads();
    int beg = bbase[blockIdx.x], end = bbase[blockIdx.x + 1];
    for (int e = beg + threadIdx.x; e < end; e += 256) {
        unsigned p = bdata[e];
        int pos = atomicAdd(&cur[p >> 20], 1);
        srcs[pos] = (int)(p & 0xFFFFFu);
    }
}

// ---------- degree scan ----------

__global__ void scanA_kernel(const int* __restrict__ cnt, int* __restrict__ rp,
                             int* __restrict__ bsum, int N) {
    __shared__ int sd[256];
    int tid = threadIdx.x;
    int base = blockIdx.x * 2048 + tid * 8;
    int v[8];
    int s = 0;
#pragma unroll
    for (int j = 0; j < 8; j++) {
        v[j] = (base + j < N) ? cnt[base + j] : 0;
        s += v[j];
    }
    sd[tid] = s;
    __syncthreads();
    for (int off = 1; off < 256; off <<= 1) {
        int t = (tid >= off) ? sd[tid - off] : 0;
        __syncthreads();
        sd[tid] += t;
        __syncthreads();
    }
    int run = sd[tid] - s;
#pragma unroll
    for (int j = 0; j < 8; j++) {
        if (base + j < N) rp[base + j] = run;
        run += v[j];
    }
    if (tid == 255) bsum[blockIdx.x] = sd[255];
}

__global__ void scanB_kernel(int* bsum, int* rp, int nb, int N) {
    int lane = threadIdx.x;
    if (nb <= 64) {
        int v = (lane < nb) ? bsum[lane] : 0;
        int orig = v;
#pragma unroll
        for (int off = 1; off < 64; off <<= 1) {
            int t = __shfl_up(v, off);
            if (lane >= off) v += t;
        }
        if (lane < nb) bsum[lane] = v - orig;
        if (lane == 63) rp[N] = v;
    } else if (lane == 0) {
        int run = 0;
        for (int b = 0; b < nb; b++) {
            int t = bsum[b];
            bsum[b] = run;
            run += t;
        }
        rp[N] = run;
    }
}

__global__ void scanC_kernel(int* __restrict__ rp, const int* __restrict__ bsum,
                             const int* __restrict__ cnt, float* __restrict__ dinv, int N) {
    int i = blockIdx.x * blockDim.x + threadIdx.x;
    if (i < N) {
        rp[i] = rp[i] + bsum[i >> 11];
        dinv[i] = rsqrtf((float)cnt[i] + 1.0f);
    }
}

// ---------- W pre-swizzle into MFMA B-fragment order ----------

__global__ void prep_w(const float* __restrict__ W1, const float* __restrict__ W2,
                       ushort* __restrict__ wsw1, ushort* __restrict__ wsw2) {
    int t = blockIdx.x * blockDim.x + threadIdx.x;
    if (t < 128 * 64) {
        int k = t >> 6, n = t & 63;
        wsw1[((k >> 3) * 64 + n) * 8 + (k & 7)] = f2bf(W1[t]);
    }
    if (t < 64 * 64) {
        int k = t >> 6, n = t & 63;
        wsw2[((k >> 3) * 64 + n) * 8 + (k & 7)] = f2bf(W2[t]);
    }
}

// ---------- matmul1: Ht[N,64](bf16) = dinv[r] * (X[N,128](fp32) @ W1) ----------

__global__ void __launch_bounds__(256) mm1_kernel(const float* __restrict__ X,
                                                  const ushort* __restrict__ wsw,
                                                  const float* __restrict__ dinv,
                                                  ushort* __restrict__ Ht, int N) {
    const int KO = 4;
    int w = threadIdx.x >> 6, lane = threadIdx.x & 63;
    int m = lane & 15, q = lane >> 4;
    int row = blockIdx.x * 64 + w * 16 + m;

    bf16x8 afrag[KO];
#pragma unroll
    for (int kk = 0; kk < KO; kk++) {
        float xv[8];
        if (row < N) {
            const float4* xp = reinterpret_cast<const float4*>(X + (size_t)row * 128 + kk * 32 + q * 8);
            float4 v0 = xp[0], v1 = xp[1];
            xv[0] = v0.x; xv[1] = v0.y; xv[2] = v0.z; xv[3] = v0.w;
            xv[4] = v1.x; xv[5] = v1.y; xv[6] = v1.z; xv[7] = v1.w;
        } else {
#pragma unroll
            for (int j = 0; j < 8; j++) xv[j] = 0.f;
        }
#pragma unroll
        for (int j = 0; j < 8; j++) afrag[kk][j] = (short)f2bf(xv[j]);
    }

    float dv[4];
#pragma unroll
    for (int reg = 0; reg < 4; reg++) {
        int r = blockIdx.x * 64 + w * 16 + q * 4 + reg;
        dv[reg] = (r < N) ? dinv[r] : 0.f;
    }

    const bf16x8* wp = reinterpret_cast<const bf16x8*>(wsw);
#pragma unroll
    for (int ct = 0; ct < 4; ct++) {
        f32x4 acc = {0.f, 0.f, 0.f, 0.f};
#pragma unroll
        for (int kk = 0; kk < KO; kk++) {
            bf16x8 b = wp[(kk * 4 + q) * 64 + ct * 16 + m];
            acc = __builtin_amdgcn_mfma_f32_16x16x32_bf16(afrag[kk], b, acc, 0, 0, 0);
        }
#pragma unroll
        for (int reg = 0; reg < 4; reg++) {
            int r = blockIdx.x * 64 + w * 16 + q * 4 + reg;
            if (r < N) Ht[(size_t)r * 64 + ct * 16 + m] = f2bf(acc[reg] * dv[reg]);
        }
    }
}

// ---------- matmul2: fused GraphNorm+LayerNorm on A, then Ht2 = dinv * (norm(A) @ W2) ----------

__global__ void __launch_bounds__(256) mm2_kernel(
    const ushort* __restrict__ A2, const ushort* __restrict__ wsw,
    const float* __restrict__ sums, const float* __restrict__ gn_w,
    const float* __restrict__ gn_b, const float* __restrict__ gn_ms,
    const float* __restrict__ ln_w, const float* __restrict__ ln_b,
    const float* __restrict__ dinv, ushort* __restrict__ Ht, int N) {
    __shared__ float sg[64], tg[64], lwv[64], lbv[64];
    int t = threadIdx.x;
    if (t < 64) {
        float invN = 1.0f / (float)N;
        float mean = sums[t] * invN;
        float m2 = sums[64 + t] * invN;
        float ms = gn_ms[t];
        float var = m2 - 2.f * ms * mean * mean + ms * ms * mean * mean;
        float s = gn_w[t] * rsqrtf(var + EPSV);
        sg[t] = s;
        tg[t] = gn_b[t] - s * ms * mean;
        lwv[t] = ln_w[t];
        lbv[t] = ln_b[t];
    }
    __syncthreads();

    int w = t >> 6, lane = t & 63;
    int m = lane & 15, q = lane >> 4;
    int row = blockIdx.x * 64 + w * 16 + m;

    float g[16];
#pragma unroll
    for (int kk = 0; kk < 2; kk++) {
        uint4 u = make_uint4(0, 0, 0, 0);
        if (row < N)
            u = *reinterpret_cast<const uint4*>(A2 + (size_t)row * 64 + kk * 32 + q * 8);
        unsigned uu[4] = {u.x, u.y, u.z, u.w};
#pragma unroll
        for (int p = 0; p < 4; p++) {
            int f0 = kk * 32 + q * 8 + 2 * p;
            g[kk * 8 + 2 * p] = sg[f0] * bf2f((ushort)uu[p]) + tg[f0];
            g[kk * 8 + 2 * p + 1] = sg[f0 + 1] * bf2f((ushort)(uu[p] >> 16)) + tg[f0 + 1];
        }
    }
    float s1 = 0.f;
#pragma unroll
    for (int i = 0; i < 16; i++) s1 += g[i];
    s1 += __shfl_xor(s1, 16);
    s1 += __shfl_xor(s1, 32);
    float mu = s1 * (1.f / 64.f);
    float s2 = 0.f;
#pragma unroll
    for (int i = 0; i < 16; i++) {
        float c = g[i] - mu;
        s2 += c * c;
    }
    s2 += __shfl_xor(s2, 16);
    s2 += __shfl_xor(s2, 32);
    float rs = rsqrtf(s2 * (1.f / 64.f) + EPSV);

    bf16x8 afrag[2];
#pragma unroll
    for (int kk = 0; kk < 2; kk++) {
#pragma unroll
        for (int j = 0; j < 8; j++) {
            int f = kk * 32 + q * 8 + j;
            float y = lwv[f] * (g[kk * 8 + j] - mu) * rs + lbv[f];
            afrag[kk][j] = (short)f2bf(y);
        }
    }

    float dv[4];
#pragma unroll
    for (int reg = 0; reg < 4; reg++) {
        int r = blockIdx.x * 64 + w * 16 + q * 4 + reg;
        dv[reg] = (r < N) ? dinv[r] : 0.f;
    }

    const bf16x8* wp = reinterpret_cast<const bf16x8*>(wsw);
#pragma unroll
    for (int ct = 0; ct < 4; ct++) {
        f32x4 acc = {0.f, 0.f, 0.f, 0.f};
#pragma unroll
        for (int kk = 0; kk < 2; kk++) {
            bf16x8 b = wp[(kk * 4 + q) * 64 + ct * 16 + m];
            acc = __builtin_amdgcn_mfma_f32_16x16x32_bf16(afrag[kk], b, acc, 0, 0, 0);
        }
#pragma unroll
        for (int reg = 0; reg < 4; reg++) {
            int r = blockIdx.x * 64 + w * 16 + q * 4 + reg;
            if (r < N) Ht[(size_t)r * 64 + ct * 16 + m] = f2bf(acc[reg] * dv[reg]);
        }
    }
}

// ---------- edge aggregation (bf16 gather, fused column stats) ----------

__global__ void __launch_bounds__(256) agg_kernel(
    const ushort* __restrict__ Ht, const int* __restrict__ rp, const int* __restrict__ srcs,
    const float* __restrict__ dinv, const float* __restrict__ bias,
    ushort* __restrict__ out, float* __restrict__ sums, int N) {
    int gw = (blockIdx.x * blockDim.x + threadIdx.x) >> 6;
    int nw = (gridDim.x * blockDim.x) >> 6;
    int lane = threadIdx.x & 63, half = lane >> 5, fl = lane & 31;
    const unsigned* H32 = reinterpret_cast<const unsigned*>(Ht);
    unsigned* out32 = reinterpret_cast<unsigned*>(out);
    float bx = bias[2 * fl], by = bias[2 * fl + 1];
    float ps1x = 0.f, ps1y = 0.f, ps2x = 0.f, ps2y = 0.f;

    for (int i = gw; i < N; i += nw) {
        int beg = rp[i], end = rp[i + 1];
        float di = dinv[i];
        float ax0 = 0.f, ay0 = 0.f, ax1 = 0.f, ay1 = 0.f;
        int e = beg + half;
        for (; e + 2 < end; e += 4) {
            int s0 = srcs[e], s1 = srcs[e + 2];
            unsigned u0 = H32[(size_t)s0 * 32 + fl];
            unsigned u1 = H32[(size_t)s1 * 32 + fl];
            ax0 += bf2f((ushort)u0); ay0 += bf2f((ushort)(u0 >> 16));
            ax1 += bf2f((ushort)u1); ay1 += bf2f((ushort)(u1 >> 16));
        }
        if (e < end) {
            unsigned u = H32[(size_t)srcs[e] * 32 + fl];
            ax0 += bf2f((ushort)u); ay0 += bf2f((ushort)(u >> 16));
        }
        float ax = ax0 + ax1, ay = ay0 + ay1;
        ax += __shfl_xor(ax, 32);
        ay += __shfl_xor(ay, 32);
        unsigned us = H32[(size_t)i * 32 + fl];
        float vx = fmaxf(di * ax + di * bf2f((ushort)us) + bx, 0.f);
        float vy = fmaxf(di * ay + di * bf2f((ushort)(us >> 16)) + by, 0.f);
        if (half == 0) {
            out32[(size_t)i * 32 + fl] = (unsigned)f2bf(vx) | ((unsigned)f2bf(vy) << 16);
            ps1x += vx; ps1y += vy;
            ps2x += vx * vx; ps2y += vy * vy;
        }
    }

    __shared__ float red[4][32][4];
    int wv = threadIdx.x >> 6;
    if (half == 0) {
        red[wv][fl][0] = ps1x; red[wv][fl][1] = ps1y;
        red[wv][fl][2] = ps2x; red[wv][fl][3] = ps2y;
    }
    __syncthreads();
    if (threadIdx.x < 128) {
        int f2 = threadIdx.x >> 2, c = threadIdx.x & 3;
        float v = red[0][f2][c] + red[1][f2][c] + red[2][f2][c] + red[3][f2][c];
        int f = 2 * f2 + (c & 1);
        atomicAdd(&sums[(c >> 1) * 64 + f], v);
    }
}

// ---------- layer-2 norms + max-pool ----------

__device__ __forceinline__ float gn_ln_row(float x, float mean, float var, float ms, float gw,
                                           float gb, float lw, float lb) {
    float g = gw * (x - ms * mean) * rsqrtf(var + EPSV) + gb;
    float mu = g;
#pragma unroll
    for (int off = 32; off; off >>= 1) mu += __shfl_xor(mu, off);
    mu *= (1.f / 64.f);
    float c = g - mu;
    float vv = c * c;
#pragma unroll
    for (int off = 32; off; off >>= 1) vv += __shfl_xor(vv, off);
    vv *= (1.f / 64.f);
    return lw * c * rsqrtf(vv + EPSV) + lb;
}

__device__ __forceinline__ unsigned fkey(float f) {
    unsigned u = __float_as_uint(f);
    return (u & 0x80000000u) ? ~u : (u | 0x80000000u);
}

__global__ void gnlnmax_kernel(const ushort* __restrict__ A, const float* __restrict__ sums,
                               const float* __restrict__ gn_w, const float* __restrict__ gn_b,
                               const float* __restrict__ gn_ms, const float* __restrict__ ln_w,
                               const float* __restrict__ ln_b, unsigned* __restrict__ pooled,
                               int N) {
    __shared__ float lmax[256];
    int lane = threadIdx.x & 63;
    int wave0 = (blockIdx.x * blockDim.x + threadIdx.x) >> 6;
    int nw = (gridDim.x * blockDim.x) >> 6;
    float invN = 1.0f / (float)N;
    float mean = sums[lane] * invN;
    float m2 = sums[64 + lane] * invN;
    float ms = gn_ms[lane];
    float var = m2 - 2.f * ms * mean * mean + ms * ms * mean * mean;
    float gw = gn_w[lane], gb = gn_b[lane], lw = ln_w[lane], lb = ln_b[lane];
    float mx = -3.4e38f;
    for (int i = wave0; i < N; i += nw) {
        float y = gn_ln_row(bf2f(A[(size_t)i * 64 + lane]), mean, var, ms, gw, gb, lw, lb);
        mx = fmaxf(mx, y);
    }
    lmax[threadIdx.x] = mx;
    __syncthreads();
    if (threadIdx.x < 64) {
        float m = fmaxf(fmaxf(lmax[threadIdx.x], lmax[threadIdx.x + 64]),
                        fmaxf(lmax[threadIdx.x + 128], lmax[threadIdx.x + 192]));
        atomicMax(&pooled[threadIdx.x], fkey(m));
    }
}

// ---------- final FC ----------

__global__ void final_kernel(const unsigned* __restrict__ pooled, const float* __restrict__ fc_W,
                             const float* __restrict__ fc_b, float* __restrict__ out) {
    __shared__ float p[64];
    int t = threadIdx.x;
    if (t < 64) {
        unsigned u = pooled[t];
        p[t] = (u & 0x80000000u) ? __uint_as_float(u ^ 0x80000000u) : __uint_as_float(~u);
    }
    __syncthreads();
    if (t < 32) {
        float acc = fc_b[t];
#pragma unroll
        for (int f = 0; f < 64; f++) acc += p[f] * fc_W[f * 32 + t];
        out[t] = acc;
    }
}

// ---------- launch ----------

static inline size_t align_up(size_t v, size_t a) { return (v + a - 1) & ~(a - 1); }

extern "C" void kernel_launch(void* const* d_in, const int* in_sizes, int n_in, void* d_out,
                              int out_size, void* d_ws, size_t ws_size, hipStream_t stream) {
    const float* x = (const float*)d_in[0];
    const int* ei = (const int*)d_in[1];
    const float* W1 = (const float*)d_in[2];
    const float* b1 = (const float*)d_in[3];
    const float* W2 = (const float*)d_in[4];
    const float* b2 = (const float*)d_in[5];
    const float* gn_w = (const float*)d_in[6];
    const float* gn_b = (const float*)d_in[7];
    const float* gn_ms = (const float*)d_in[8];
    const float* ln_w = (const float*)d_in[9];
    const float* ln_b = (const float*)d_in[10];
    const float* fc_W = (const float*)d_in[11];
    const float* fc_b = (const float*)d_in[12];
    float* out = (float*)d_out;

    const int N = in_sizes[0] / 128;
    const int E = in_sizes[1] / 2;
    const int NB = (N + CHUNK - 1) / CHUNK;

    char* ws = (char*)d_ws;
    size_t off = 0;
    auto alloc = [&](size_t bytes) {
        char* p = ws + off;
        off = align_up(off + bytes, 256);
        return p;
    };
    int* cnt = (int*)alloc((size_t)N * 4);
    int* rp = (int*)alloc((size_t)(N + 1) * 4);
    int* bsum = (int*)alloc(256 * 4);
    int* bcnt = (int*)alloc((size_t)(NB + 1) * 4);
    int* bbase = (int*)alloc((size_t)(NB + 1) * 4);
    int* bcur = (int*)alloc((size_t)(NB + 1) * 4);
    float* dinv = (float*)alloc((size_t)N * 4);
    unsigned* bdata = (unsigned*)alloc((size_t)E * 4);
    int* srcs = (int*)alloc((size_t)E * 4);
    ushort* bufA = (ushort*)alloc((size_t)N * 64 * 2);
    ushort* bufB = (ushort*)alloc((size_t)N * 64 * 2);
    ushort* wsw1 = (ushort*)alloc(128 * 64 * 2);
    ushort* wsw2 = (ushort*)alloc(64 * 64 * 2);
    float* sums = (float*)alloc(256 * 4);
    unsigned* pooled = (unsigned*)alloc(64 * 4);

    hipMemsetAsync(bcnt, 0, (size_t)(NB + 1) * 4, stream);
    hipMemsetAsync(sums, 0, 256 * 4, stream);
    hipMemsetAsync(pooled, 0, 64 * 4, stream);

    prep_w<<<32, 256, 0, stream>>>(W1, W2, wsw1, wsw2);

    // CSR build (bucketed, no random global writes/atomics)
    int nbScan = (N + 2047) / 2048;
    int nbB = (E + EPB - 1) / EPB;
    bucket_hist<<<256, 256, 0, stream>>>(ei, bcnt, E, NB);
    bucket_scan<<<1, MAXNB, 0, stream>>>(bcnt, bbase, bcur, NB);
    bucket_scatter<<<nbB, 256, 0, stream>>>(ei, bcur, bdata, E, NB);
    fine_hist<<<NB, 256, 0, stream>>>(bdata, bbase, cnt, N);
    scanA_kernel<<<nbScan, 256, 0, stream>>>(cnt, rp, bsum, N);
    scanB_kernel<<<1, 64, 0, stream>>>(bsum, rp, nbScan, N);
    scanC_kernel<<<(N + 255) / 256, 256, 0, stream>>>(rp, bsum, cnt, dinv, N);
    fine_scatter<<<NB, 256, 0, stream>>>(bdata, bbase, rp, srcs, N);

    int nbMM = (N + 63) / 64;

    // Layer 1
    mm1_kernel<<<nbMM, 256, 0, stream>>>(x, wsw1, dinv, bufA, N);
    agg_kernel<<<2048, 256, 0, stream>>>(bufA, rp, srcs, dinv, b1, bufB, sums, N);

    // Layer 2
    mm2_kernel<<<nbMM, 256, 0, stream>>>(bufB, wsw2, sums, gn_w, gn_b, gn_ms, ln_w, ln_b, dinv,
                                         bufA, N);
    agg_kernel<<<2048, 256, 0, stream>>>(bufA, rp, srcs, dinv, b2, bufB, sums + 128, N);
    gnlnmax_kernel<<<512, 256, 0, stream>>>(bufB, sums + 128, gn_w, gn_b, gn_ms, ln_w, ln_b,
                                            pooled, N);

    final_kernel<<<1, 64, 0, stream>>>(pooled, fc_W, fc_b, out);
}

// Round 5
// 397.916 us; speedup vs baseline: 1.9682x; 1.1213x over previous
//
#include <hip/hip_runtime.h>
#include <hip/hip_bf16.h>

#define EPSV 1e-5f
#define CHUNK 256   // dst nodes per bucket (bucket = dst >> 8)
#define MAXNB 512   // supports N <= 131072

typedef __attribute__((ext_vector_type(8))) short bf16x8;
typedef __attribute__((ext_vector_type(4))) float f32x4;

__device__ __forceinline__ ushort f2bf(float f) {
    union { float f; unsigned u; } c; c.f = f;
    unsigned u = c.u;
    return (ushort)((u + 0x7fffu + ((u >> 16) & 1u)) >> 16);
}
__device__ __forceinline__ float bf2f(ushort h) {
    union { unsigned u; float f; } c; c.u = ((unsigned)h) << 16;
    return c.f;
}
__device__ __forceinline__ void acc2(float& a, float& b, unsigned p) {
    a += bf2f((ushort)p);
    b += bf2f((ushort)(p >> 16));
}

// ---------- bucketed CSR build ----------
// pack: low 20 bits = src (N < 2^20), bits 20..27 = dst & 255

__global__ void bucket_hist(const int* __restrict__ ei, int* __restrict__ bcnt, int E, int NB) {
    __shared__ int h[MAXNB];
    for (int b = threadIdx.x; b < NB; b += 256) h[b] = 0;
    __syncthreads();
    int stride = gridDim.x * 256;
    for (int e = blockIdx.x * 256 + threadIdx.x; e < E; e += stride)
        atomicAdd(&h[ei[E + e] >> 8], 1);
    __syncthreads();
    for (int b = threadIdx.x; b < NB; b += 256)
        if (h[b]) atomicAdd(&bcnt[b], h[b]);
}

__global__ void bucket_scan(const int* __restrict__ bcnt, int* __restrict__ bbase,
                            int* __restrict__ bcur, int* __restrict__ rp, int NB, int N) {
    __shared__ int sd[MAXNB];
    int t = threadIdx.x;
    int v = (t < NB) ? bcnt[t] : 0;
    sd[t] = v;
    __syncthreads();
    for (int off = 1; off < MAXNB; off <<= 1) {
        int x = (t >= off) ? sd[t - off] : 0;
        __syncthreads();
        sd[t] += x;
        __syncthreads();
    }
    int excl = sd[t] - v;
    if (t < NB) { bbase[t] = excl; bcur[t] = excl; }
    if (t == MAXNB - 1) {
        bbase[NB] = sd[MAXNB - 1];
        rp[N] = sd[MAXNB - 1];  // == E
    }
}

#define EPB 8192  // edges per bucket_scatter block

__global__ void __launch_bounds__(256) bucket_scatter(const int* __restrict__ ei,
                                                      int* __restrict__ bcur,
                                                      unsigned* __restrict__ bdata, int E,
                                                      int NB) {
    __shared__ int h[MAXNB];
    __shared__ int cur[MAXNB];
    int base = blockIdx.x * EPB;
    int end = min(base + EPB, E);
    for (int b = threadIdx.x; b < NB; b += 256) h[b] = 0;
    __syncthreads();
    for (int e = base + threadIdx.x; e < end; e += 256)
        atomicAdd(&h[ei[E + e] >> 8], 1);
    __syncthreads();
    for (int b = threadIdx.x; b < NB; b += 256) {
        int c = h[b];
        cur[b] = c ? atomicAdd(&bcur[b], c) : 0;
    }
    __syncthreads();
    for (int e = base + threadIdx.x; e < end; e += 256) {
        int s = ei[e], d = ei[E + e];
        int pos = atomicAdd(&cur[d >> 8], 1);
        bdata[pos] = (unsigned)s | ((unsigned)(d & (CHUNK - 1)) << 20);
    }
}

// fused: per-bucket hist -> local scan -> rp/dinv -> scatter (srcs pre-shifted: src*16)
__global__ void __launch_bounds__(256) bucket_finish(const unsigned* __restrict__ bdata,
                                                     const int* __restrict__ bbase,
                                                     int* __restrict__ rp,
                                                     float* __restrict__ dinv,
                                                     int* __restrict__ srcs, int N) {
    __shared__ int h[CHUNK];
    __shared__ int cur[CHUNK];
    int t = threadIdx.x;
    h[t] = 0;
    __syncthreads();
    int beg = bbase[blockIdx.x], end = bbase[blockIdx.x + 1];
    for (int e = beg + t; e < end; e += 256) atomicAdd(&h[bdata[e] >> 20], 1);
    __syncthreads();
    int v = h[t];
    cur[t] = v;
    __syncthreads();
    for (int off = 1; off < 256; off <<= 1) {
        int x = (t >= off) ? cur[t - off] : 0;
        __syncthreads();
        cur[t] += x;
        __syncthreads();
    }
    int r = beg + cur[t] - v;  // exclusive prefix within bucket
    int node = blockIdx.x * CHUNK + t;
    if (node < N) {
        rp[node] = r;
        dinv[node] = rsqrtf((float)v + 1.0f);
    }
    cur[t] = r;
    __syncthreads();
    for (int e = beg + t; e < end; e += 256) {
        unsigned p = bdata[e];
        int pos = atomicAdd(&cur[p >> 20], 1);
        srcs[pos] = (int)((p & 0xFFFFFu) << 4);  // src * 16 (uint2 row offset)
    }
}

// ---------- W pre-swizzle into MFMA B-fragment order ----------

__global__ void prep_w(const float* __restrict__ W1, const float* __restrict__ W2,
                       ushort* __restrict__ wsw1, ushort* __restrict__ wsw2) {
    int t = blockIdx.x * blockDim.x + threadIdx.x;
    if (t < 128 * 64) {
        int k = t >> 6, n = t & 63;
        wsw1[((k >> 3) * 64 + n) * 8 + (k & 7)] = f2bf(W1[t]);
    }
    if (t < 64 * 64) {
        int k = t >> 6, n = t & 63;
        wsw2[((k >> 3) * 64 + n) * 8 + (k & 7)] = f2bf(W2[t]);
    }
}

// ---------- matmul1: Ht[N,64](bf16) = dinv[r] * (X[N,128](fp32) @ W1) ----------

__global__ void __launch_bounds__(256) mm1_kernel(const float* __restrict__ X,
                                                  const ushort* __restrict__ wsw,
                                                  const float* __restrict__ dinv,
                                                  ushort* __restrict__ Ht, int N) {
    const int KO = 4;
    int w = threadIdx.x >> 6, lane = threadIdx.x & 63;
    int m = lane & 15, q = lane >> 4;
    int row = blockIdx.x * 64 + w * 16 + m;

    bf16x8 afrag[KO];
#pragma unroll
    for (int kk = 0; kk < KO; kk++) {
        float xv[8];
        if (row < N) {
            const float4* xp = reinterpret_cast<const float4*>(X + (size_t)row * 128 + kk * 32 + q * 8);
            float4 v0 = xp[0], v1 = xp[1];
            xv[0] = v0.x; xv[1] = v0.y; xv[2] = v0.z; xv[3] = v0.w;
            xv[4] = v1.x; xv[5] = v1.y; xv[6] = v1.z; xv[7] = v1.w;
        } else {
#pragma unroll
            for (int j = 0; j < 8; j++) xv[j] = 0.f;
        }
#pragma unroll
        for (int j = 0; j < 8; j++) afrag[kk][j] = (short)f2bf(xv[j]);
    }

    float dv[4];
#pragma unroll
    for (int reg = 0; reg < 4; reg++) {
        int r = blockIdx.x * 64 + w * 16 + q * 4 + reg;
        dv[reg] = (r < N) ? dinv[r] : 0.f;
    }

    const bf16x8* wp = reinterpret_cast<const bf16x8*>(wsw);
#pragma unroll
    for (int ct = 0; ct < 4; ct++) {
        f32x4 acc = {0.f, 0.f, 0.f, 0.f};
#pragma unroll
        for (int kk = 0; kk < KO; kk++) {
            bf16x8 b = wp[(kk * 4 + q) * 64 + ct * 16 + m];
            acc = __builtin_amdgcn_mfma_f32_16x16x32_bf16(afrag[kk], b, acc, 0, 0, 0);
        }
#pragma unroll
        for (int reg = 0; reg < 4; reg++) {
            int r = blockIdx.x * 64 + w * 16 + q * 4 + reg;
            if (r < N) Ht[(size_t)r * 64 + ct * 16 + m] = f2bf(acc[reg] * dv[reg]);
        }
    }
}

// ---------- matmul2: fused GraphNorm+LayerNorm on A, then Ht2 = dinv * (norm(A) @ W2) ----------

__global__ void __launch_bounds__(256) mm2_kernel(
    const ushort* __restrict__ A2, const ushort* __restrict__ wsw,
    const float* __restrict__ sums, const float* __restrict__ gn_w,
    const float* __restrict__ gn_b, const float* __restrict__ gn_ms,
    const float* __restrict__ ln_w, const float* __restrict__ ln_b,
    const float* __restrict__ dinv, ushort* __restrict__ Ht, int N) {
    __shared__ float sg[64], tg[64], lwv[64], lbv[64];
    int t = threadIdx.x;
    if (t < 64) {
        float invN = 1.0f / (float)N;
        float mean = sums[t] * invN;
        float m2 = sums[64 + t] * invN;
        float ms = gn_ms[t];
        float var = m2 - 2.f * ms * mean * mean + ms * ms * mean * mean;
        float s = gn_w[t] * rsqrtf(var + EPSV);
        sg[t] = s;
        tg[t] = gn_b[t] - s * ms * mean;
        lwv[t] = ln_w[t];
        lbv[t] = ln_b[t];
    }
    __syncthreads();

    int w = t >> 6, lane = t & 63;
    int m = lane & 15, q = lane >> 4;
    int row = blockIdx.x * 64 + w * 16 + m;

    float g[16];
#pragma unroll
    for (int kk = 0; kk < 2; kk++) {
        uint4 u = make_uint4(0, 0, 0, 0);
        if (row < N)
            u = *reinterpret_cast<const uint4*>(A2 + (size_t)row * 64 + kk * 32 + q * 8);
        unsigned uu[4] = {u.x, u.y, u.z, u.w};
#pragma unroll
        for (int p = 0; p < 4; p++) {
            int f0 = kk * 32 + q * 8 + 2 * p;
            g[kk * 8 + 2 * p] = sg[f0] * bf2f((ushort)uu[p]) + tg[f0];
            g[kk * 8 + 2 * p + 1] = sg[f0 + 1] * bf2f((ushort)(uu[p] >> 16)) + tg[f0 + 1];
        }
    }
    float s1 = 0.f;
#pragma unroll
    for (int i = 0; i < 16; i++) s1 += g[i];
    s1 += __shfl_xor(s1, 16);
    s1 += __shfl_xor(s1, 32);
    float mu = s1 * (1.f / 64.f);
    float s2 = 0.f;
#pragma unroll
    for (int i = 0; i < 16; i++) {
        float c = g[i] - mu;
        s2 += c * c;
    }
    s2 += __shfl_xor(s2, 16);
    s2 += __shfl_xor(s2, 32);
    float rs = rsqrtf(s2 * (1.f / 64.f) + EPSV);

    bf16x8 afrag[2];
#pragma unroll
    for (int kk = 0; kk < 2; kk++) {
#pragma unroll
        for (int j = 0; j < 8; j++) {
            int f = kk * 32 + q * 8 + j;
            float y = lwv[f] * (g[kk * 8 + j] - mu) * rs + lbv[f];
            afrag[kk][j] = (short)f2bf(y);
        }
    }

    float dv[4];
#pragma unroll
    for (int reg = 0; reg < 4; reg++) {
        int r = blockIdx.x * 64 + w * 16 + q * 4 + reg;
        dv[reg] = (r < N) ? dinv[r] : 0.f;
    }

    const bf16x8* wp = reinterpret_cast<const bf16x8*>(wsw);
#pragma unroll
    for (int ct = 0; ct < 4; ct++) {
        f32x4 acc = {0.f, 0.f, 0.f, 0.f};
#pragma unroll
        for (int kk = 0; kk < 2; kk++) {
            bf16x8 b = wp[(kk * 4 + q) * 64 + ct * 16 + m];
            acc = __builtin_amdgcn_mfma_f32_16x16x32_bf16(afrag[kk], b, acc, 0, 0, 0);
        }
#pragma unroll
        for (int reg = 0; reg < 4; reg++) {
            int r = blockIdx.x * 64 + w * 16 + q * 4 + reg;
            if (r < N) Ht[(size_t)r * 64 + ct * 16 + m] = f2bf(acc[reg] * dv[reg]);
        }
    }
}

// ---------- edge aggregation v3: batched indices, CONVERGED shfls, zero-row clamp ----------
// wave per node; srcs holds src*16; lane = g*16+fq. All shfls run with the full wave
// active (uniform chunk loop over bn, which is wave-uniform); out-of-range edge slots
// are clamped to the zero row at Ht[N] (branchless), keeping 4 row-loads in flight.

__global__ void __launch_bounds__(256) agg_kernel(
    const ushort* __restrict__ Ht, const int* __restrict__ rp, const int* __restrict__ srcs,
    const float* __restrict__ dinv, const float* __restrict__ bias,
    ushort* __restrict__ out, float* __restrict__ sums, int N) {
    int wid = (blockIdx.x * blockDim.x + threadIdx.x) >> 6;
    int nw = (gridDim.x * blockDim.x) >> 6;
    int lane = threadIdx.x & 63;
    int g = lane >> 4, fq = lane & 15;
    const int ZROW = N * 16;  // zero row (uint2 offset)
    const uint2* H2 = reinterpret_cast<const uint2*>(Ht);
    uint2* O2 = reinterpret_cast<uint2*>(out);
    float bb0 = bias[4 * fq], bb1 = bias[4 * fq + 1], bb2 = bias[4 * fq + 2],
          bb3 = bias[4 * fq + 3];
    float ps1[4] = {0, 0, 0, 0}, ps2[4] = {0, 0, 0, 0};

    for (int i = wid; i < N; i += nw) {
        int beg = rp[i], end = rp[i + 1];
        int deg = end - beg;
        float a0 = 0.f, a1 = 0.f, a2 = 0.f, a3 = 0.f;
        for (int base = 0; base < deg; base += 64) {
            int bn = deg - base;
            if (bn > 64) bn = 64;
            int sv = (lane < bn) ? srcs[beg + base + lane] : ZROW;
            for (int kb = 0; kb < bn; kb += 16) {  // bn wave-uniform: no divergence
                int e = kb + g;
                int s0 = __shfl(sv, e);
                int s1 = __shfl(sv, e + 4);
                int s2 = __shfl(sv, e + 8);
                int s3 = __shfl(sv, e + 12);
                s0 = (e < bn) ? s0 : ZROW;
                s1 = (e + 4 < bn) ? s1 : ZROW;
                s2 = (e + 8 < bn) ? s2 : ZROW;
                s3 = (e + 12 < bn) ? s3 : ZROW;
                uint2 u0 = H2[(size_t)(unsigned)s0 + fq];
                uint2 u1 = H2[(size_t)(unsigned)s1 + fq];
                uint2 u2 = H2[(size_t)(unsigned)s2 + fq];
                uint2 u3 = H2[(size_t)(unsigned)s3 + fq];
                acc2(a0, a1, u0.x); acc2(a2, a3, u0.y);
                acc2(a0, a1, u1.x); acc2(a2, a3, u1.y);
                acc2(a0, a1, u2.x); acc2(a2, a3, u2.y);
                acc2(a0, a1, u3.x); acc2(a2, a3, u3.y);
            }
        }
        // reduce across the 4 groups (feature-quad fq identical across groups)
        a0 += __shfl_xor(a0, 16); a0 += __shfl_xor(a0, 32);
        a1 += __shfl_xor(a1, 16); a1 += __shfl_xor(a1, 32);
        a2 += __shfl_xor(a2, 16); a2 += __shfl_xor(a2, 32);
        a3 += __shfl_xor(a3, 16); a3 += __shfl_xor(a3, 32);

        float di = dinv[i];
        uint2 us = H2[(size_t)i * 16 + fq];
        float v0 = fmaxf(di * a0 + di * bf2f((ushort)us.x) + bb0, 0.f);
        float v1 = fmaxf(di * a1 + di * bf2f((ushort)(us.x >> 16)) + bb1, 0.f);
        float v2 = fmaxf(di * a2 + di * bf2f((ushort)us.y) + bb2, 0.f);
        float v3 = fmaxf(di * a3 + di * bf2f((ushort)(us.y >> 16)) + bb3, 0.f);
        if (g == 0) {
            uint2 o;
            o.x = (unsigned)f2bf(v0) | ((unsigned)f2bf(v1) << 16);
            o.y = (unsigned)f2bf(v2) | ((unsigned)f2bf(v3) << 16);
            O2[(size_t)i * 16 + fq] = o;
            ps1[0] += v0; ps1[1] += v1; ps1[2] += v2; ps1[3] += v3;
            ps2[0] += v0 * v0; ps2[1] += v1 * v1; ps2[2] += v2 * v2; ps2[3] += v3 * v3;
        }
    }

    __shared__ float red[4][16][8];
    int wv = threadIdx.x >> 6;
    if (g == 0) {
#pragma unroll
        for (int p = 0; p < 4; p++) {
            red[wv][fq][p] = ps1[p];
            red[wv][fq][4 + p] = ps2[p];
        }
    }
    __syncthreads();
    if (threadIdx.x < 128) {
        int fqq = threadIdx.x >> 3, c = threadIdx.x & 7;
        float v = red[0][fqq][c] + red[1][fqq][c] + red[2][fqq][c] + red[3][fqq][c];
        atomicAdd(&sums[(c >> 2) * 64 + fqq * 4 + (c & 3)], v);
    }
}

// ---------- layer-2 norms + max-pool ----------

__device__ __forceinline__ float gn_ln_row(float x, float mean, float var, float ms, float gw,
                                           float gb, float lw, float lb) {
    float g = gw * (x - ms * mean) * rsqrtf(var + EPSV) + gb;
    float mu = g;
#pragma unroll
    for (int off = 32; off; off >>= 1) mu += __shfl_xor(mu, off);
    mu *= (1.f / 64.f);
    float c = g - mu;
    float vv = c * c;
#pragma unroll
    for (int off = 32; off; off >>= 1) vv += __shfl_xor(vv, off);
    vv *= (1.f / 64.f);
    return lw * c * rsqrtf(vv + EPSV) + lb;
}

__device__ __forceinline__ unsigned fkey(float f) {
    unsigned u = __float_as_uint(f);
    return (u & 0x80000000u) ? ~u : (u | 0x80000000u);
}

__global__ void gnlnmax_kernel(const ushort* __restrict__ A, const float* __restrict__ sums,
                               const float* __restrict__ gn_w, const float* __restrict__ gn_b,
                               const float* __restrict__ gn_ms, const float* __restrict__ ln_w,
                               const float* __restrict__ ln_b, unsigned* __restrict__ pooled,
                               int N) {
    __shared__ float lmax[256];
    int lane = threadIdx.x & 63;
    int wave0 = (blockIdx.x * blockDim.x + threadIdx.x) >> 6;
    int nw = (gridDim.x * blockDim.x) >> 6;
    float invN = 1.0f / (float)N;
    float mean = sums[lane] * invN;
    float m2 = sums[64 + lane] * invN;
    float ms = gn_ms[lane];
    float var = m2 - 2.f * ms * mean * mean + ms * ms * mean * mean;
    float gw = gn_w[lane], gb = gn_b[lane], lw = ln_w[lane], lb = ln_b[lane];
    float mx = -3.4e38f;
    for (int i = wave0; i < N; i += nw) {
        float y = gn_ln_row(bf2f(A[(size_t)i * 64 + lane]), mean, var, ms, gw, gb, lw, lb);
        mx = fmaxf(mx, y);
    }
    lmax[threadIdx.x] = mx;
    __syncthreads();
    if (threadIdx.x < 64) {
        float m = fmaxf(fmaxf(lmax[threadIdx.x], lmax[threadIdx.x + 64]),
                        fmaxf(lmax[threadIdx.x + 128], lmax[threadIdx.x + 192]));
        atomicMax(&pooled[threadIdx.x], fkey(m));
    }
}

// ---------- final FC ----------

__global__ void final_kernel(const unsigned* __restrict__ pooled, const float* __restrict__ fc_W,
                             const float* __restrict__ fc_b, float* __restrict__ out) {
    __shared__ float p[64];
    int t = threadIdx.x;
    if (t < 64) {
        unsigned u = pooled[t];
        p[t] = (u & 0x80000000u) ? __uint_as_float(u ^ 0x80000000u) : __uint_as_float(~u);
    }
    __syncthreads();
    if (t < 32) {
        float acc = fc_b[t];
#pragma unroll
        for (int f = 0; f < 64; f++) acc += p[f] * fc_W[f * 32 + t];
        out[t] = acc;
    }
}

// ---------- launch ----------

static inline size_t align_up(size_t v, size_t a) { return (v + a - 1) & ~(a - 1); }

extern "C" void kernel_launch(void* const* d_in, const int* in_sizes, int n_in, void* d_out,
                              int out_size, void* d_ws, size_t ws_size, hipStream_t stream) {
    const float* x = (const float*)d_in[0];
    const int* ei = (const int*)d_in[1];
    const float* W1 = (const float*)d_in[2];
    const float* b1 = (const float*)d_in[3];
    const float* W2 = (const float*)d_in[4];
    const float* b2 = (const float*)d_in[5];
    const float* gn_w = (const float*)d_in[6];
    const float* gn_b = (const float*)d_in[7];
    const float* gn_ms = (const float*)d_in[8];
    const float* ln_w = (const float*)d_in[9];
    const float* ln_b = (const float*)d_in[10];
    const float* fc_W = (const float*)d_in[11];
    const float* fc_b = (const float*)d_in[12];
    float* out = (float*)d_out;

    const int N = in_sizes[0] / 128;
    const int E = in_sizes[1] / 2;
    const int NB = (N + CHUNK - 1) / CHUNK;

    char* ws = (char*)d_ws;
    size_t off = 0;
    auto alloc = [&](size_t bytes) {
        char* p = ws + off;
        off = align_up(off + bytes, 256);
        return p;
    };
    int* rp = (int*)alloc((size_t)(N + 1) * 4);
    int* bcnt = (int*)alloc((size_t)(NB + 1) * 4);
    int* bbase = (int*)alloc((size_t)(NB + 1) * 4);
    int* bcur = (int*)alloc((size_t)(NB + 1) * 4);
    float* dinv = (float*)alloc((size_t)N * 4);
    unsigned* bdata = (unsigned*)alloc((size_t)E * 4);
    int* srcs = (int*)alloc((size_t)E * 4);
    ushort* bufA = (ushort*)alloc((size_t)(N + 1) * 64 * 2);  // +1: zero row at index N
    ushort* bufB = (ushort*)alloc((size_t)(N + 1) * 64 * 2);
    ushort* wsw1 = (ushort*)alloc(128 * 64 * 2);
    ushort* wsw2 = (ushort*)alloc(64 * 64 * 2);
    float* sums = (float*)alloc(256 * 4);
    unsigned* pooled = (unsigned*)alloc(64 * 4);

    hipMemsetAsync(bcnt, 0, (size_t)(NB + 1) * 4, stream);
    hipMemsetAsync(sums, 0, 256 * 4, stream);
    hipMemsetAsync(pooled, 0, 64 * 4, stream);
    hipMemsetAsync(bufA + (size_t)N * 64, 0, 128, stream);  // zero row
    hipMemsetAsync(bufB + (size_t)N * 64, 0, 128, stream);

    prep_w<<<32, 256, 0, stream>>>(W1, W2, wsw1, wsw2);

    // CSR build (bucketed)
    int nbB = (E + EPB - 1) / EPB;
    bucket_hist<<<256, 256, 0, stream>>>(ei, bcnt, E, NB);
    bucket_scan<<<1, MAXNB, 0, stream>>>(bcnt, bbase, bcur, rp, NB, N);
    bucket_scatter<<<nbB, 256, 0, stream>>>(ei, bcur, bdata, E, NB);
    bucket_finish<<<NB, 256, 0, stream>>>(bdata, bbase, rp, dinv, srcs, N);

    int nbMM = (N + 63) / 64;

    // Layer 1
    mm1_kernel<<<nbMM, 256, 0, stream>>>(x, wsw1, dinv, bufA, N);
    agg_kernel<<<2048, 256, 0, stream>>>(bufA, rp, srcs, dinv, b1, bufB, sums, N);

    // Layer 2
    mm2_kernel<<<nbMM, 256, 0, stream>>>(bufB, wsw2, sums, gn_w, gn_b, gn_ms, ln_w, ln_b, dinv,
                                         bufA, N);
    agg_kernel<<<2048, 256, 0, stream>>>(bufA, rp, srcs, dinv, b2, bufB, sums + 128, N);
    gnlnmax_kernel<<<512, 256, 0, stream>>>(bufB, sums + 128, gn_w, gn_b, gn_ms, ln_w, ln_b,
                                            pooled, N);

    final_kernel<<<1, 64, 0, stream>>>(pooled, fc_W, fc_b, out);
}

// Round 6
// 387.559 us; speedup vs baseline: 2.0208x; 1.0267x over previous
//
#include <hip/hip_runtime.h>
#include <hip/hip_bf16.h>

#define EPSV 1e-5f
#define CHUNK 256   // dst nodes per bucket (bucket = dst >> 8)
#define MAXNB 512   // supports N <= 131072

typedef __attribute__((ext_vector_type(8))) short bf16x8;
typedef __attribute__((ext_vector_type(4))) float f32x4;

__device__ __forceinline__ ushort f2bf(float f) {
    union { float f; unsigned u; } c; c.f = f;
    unsigned u = c.u;
    return (ushort)((u + 0x7fffu + ((u >> 16) & 1u)) >> 16);
}
__device__ __forceinline__ float bf2f(ushort h) {
    union { unsigned u; float f; } c; c.u = ((unsigned)h) << 16;
    return c.f;
}
__device__ __forceinline__ void acc2(float& a, float& b, unsigned p) {
    a += bf2f((ushort)p);
    b += bf2f((ushort)(p >> 16));
}

// ---------- bucketed CSR build ----------
// pack: low 20 bits = src (N < 2^20), bits 20..27 = dst & 255

__global__ void bucket_hist(const int* __restrict__ ei, int* __restrict__ bcnt, int E, int NB) {
    __shared__ int h[MAXNB];
    for (int b = threadIdx.x; b < NB; b += 256) h[b] = 0;
    __syncthreads();
    int stride = gridDim.x * 256;
    for (int e = blockIdx.x * 256 + threadIdx.x; e < E; e += stride)
        atomicAdd(&h[ei[E + e] >> 8], 1);
    __syncthreads();
    for (int b = threadIdx.x; b < NB; b += 256)
        if (h[b]) atomicAdd(&bcnt[b], h[b]);
}

// scan over buckets + W pre-swizzle (fused: both tiny, saves a dispatch)
__global__ void bucket_scan(const int* __restrict__ bcnt, int* __restrict__ bbase,
                            int* __restrict__ bcur, int* __restrict__ rp, int NB, int N,
                            const float* __restrict__ W1, const float* __restrict__ W2,
                            ushort* __restrict__ wsw1, ushort* __restrict__ wsw2) {
    __shared__ int sd[MAXNB];
    int t = threadIdx.x;
    int v = (t < NB) ? bcnt[t] : 0;
    sd[t] = v;
    __syncthreads();
    for (int off = 1; off < MAXNB; off <<= 1) {
        int x = (t >= off) ? sd[t - off] : 0;
        __syncthreads();
        sd[t] += x;
        __syncthreads();
    }
    int excl = sd[t] - v;
    if (t < NB) { bbase[t] = excl; bcur[t] = excl; }
    if (t == MAXNB - 1) {
        bbase[NB] = sd[MAXNB - 1];
        rp[N] = sd[MAXNB - 1];  // == E
    }
    // W pre-swizzle into MFMA B-fragment order: (k,n) -> [((k>>3)*64+n)*8+(k&7)]
    for (int i = t; i < 128 * 64; i += MAXNB) {
        int k = i >> 6, n = i & 63;
        wsw1[((k >> 3) * 64 + n) * 8 + (k & 7)] = f2bf(W1[i]);
    }
    for (int i = t; i < 64 * 64; i += MAXNB) {
        int k = i >> 6, n = i & 63;
        wsw2[((k >> 3) * 64 + n) * 8 + (k & 7)] = f2bf(W2[i]);
    }
}

#define EPB 8192  // edges per bucket_scatter block

__global__ void __launch_bounds__(256) bucket_scatter(const int* __restrict__ ei,
                                                      int* __restrict__ bcur,
                                                      unsigned* __restrict__ bdata, int E,
                                                      int NB) {
    __shared__ int h[MAXNB];
    __shared__ int cur[MAXNB];
    int base = blockIdx.x * EPB;
    int end = min(base + EPB, E);
    for (int b = threadIdx.x; b < NB; b += 256) h[b] = 0;
    __syncthreads();
    for (int e = base + threadIdx.x; e < end; e += 256)
        atomicAdd(&h[ei[E + e] >> 8], 1);
    __syncthreads();
    for (int b = threadIdx.x; b < NB; b += 256) {
        int c = h[b];
        cur[b] = c ? atomicAdd(&bcur[b], c) : 0;
    }
    __syncthreads();
    for (int e = base + threadIdx.x; e < end; e += 256) {
        int s = ei[e], d = ei[E + e];
        int pos = atomicAdd(&cur[d >> 8], 1);
        bdata[pos] = (unsigned)s | ((unsigned)(d & (CHUNK - 1)) << 20);
    }
}

// fused: per-bucket hist -> local scan -> rp/dinv -> scatter (srcs pre-shifted: src*16)
__global__ void __launch_bounds__(256) bucket_finish(const unsigned* __restrict__ bdata,
                                                     const int* __restrict__ bbase,
                                                     int* __restrict__ rp,
                                                     float* __restrict__ dinv,
                                                     int* __restrict__ srcs, int N) {
    __shared__ int h[CHUNK];
    __shared__ int cur[CHUNK];
    int t = threadIdx.x;
    h[t] = 0;
    __syncthreads();
    int beg = bbase[blockIdx.x], end = bbase[blockIdx.x + 1];
    for (int e = beg + t; e < end; e += 256) atomicAdd(&h[bdata[e] >> 20], 1);
    __syncthreads();
    int v = h[t];
    cur[t] = v;
    __syncthreads();
    for (int off = 1; off < 256; off <<= 1) {
        int x = (t >= off) ? cur[t - off] : 0;
        __syncthreads();
        cur[t] += x;
        __syncthreads();
    }
    int r = beg + cur[t] - v;  // exclusive prefix within bucket
    int node = blockIdx.x * CHUNK + t;
    if (node < N) {
        rp[node] = r;
        dinv[node] = rsqrtf((float)v + 1.0f);
    }
    cur[t] = r;
    __syncthreads();
    for (int e = beg + t; e < end; e += 256) {
        unsigned p = bdata[e];
        int pos = atomicAdd(&cur[p >> 20], 1);
        srcs[pos] = (int)((p & 0xFFFFFu) << 4);  // src * 16 (uint2 row offset)
    }
}

// ---------- matmul1: Ht[N,64](bf16) = dinv[r] * (X[N,128](fp32) @ W1) ----------

__global__ void __launch_bounds__(256) mm1_kernel(const float* __restrict__ X,
                                                  const ushort* __restrict__ wsw,
                                                  const float* __restrict__ dinv,
                                                  ushort* __restrict__ Ht, int N) {
    const int KO = 4;
    int w = threadIdx.x >> 6, lane = threadIdx.x & 63;
    int m = lane & 15, q = lane >> 4;
    int row = blockIdx.x * 64 + w * 16 + m;

    bf16x8 afrag[KO];
#pragma unroll
    for (int kk = 0; kk < KO; kk++) {
        float xv[8];
        if (row < N) {
            const float4* xp = reinterpret_cast<const float4*>(X + (size_t)row * 128 + kk * 32 + q * 8);
            float4 v0 = xp[0], v1 = xp[1];
            xv[0] = v0.x; xv[1] = v0.y; xv[2] = v0.z; xv[3] = v0.w;
            xv[4] = v1.x; xv[5] = v1.y; xv[6] = v1.z; xv[7] = v1.w;
        } else {
#pragma unroll
            for (int j = 0; j < 8; j++) xv[j] = 0.f;
        }
#pragma unroll
        for (int j = 0; j < 8; j++) afrag[kk][j] = (short)f2bf(xv[j]);
    }

    float dv[4];
#pragma unroll
    for (int reg = 0; reg < 4; reg++) {
        int r = blockIdx.x * 64 + w * 16 + q * 4 + reg;
        dv[reg] = (r < N) ? dinv[r] : 0.f;
    }

    const bf16x8* wp = reinterpret_cast<const bf16x8*>(wsw);
#pragma unroll
    for (int ct = 0; ct < 4; ct++) {
        f32x4 acc = {0.f, 0.f, 0.f, 0.f};
#pragma unroll
        for (int kk = 0; kk < KO; kk++) {
            bf16x8 b = wp[(kk * 4 + q) * 64 + ct * 16 + m];
            acc = __builtin_amdgcn_mfma_f32_16x16x32_bf16(afrag[kk], b, acc, 0, 0, 0);
        }
#pragma unroll
        for (int reg = 0; reg < 4; reg++) {
            int r = blockIdx.x * 64 + w * 16 + q * 4 + reg;
            if (r < N) Ht[(size_t)r * 64 + ct * 16 + m] = f2bf(acc[reg] * dv[reg]);
        }
    }
}

// ---------- matmul2: fused GraphNorm+LayerNorm on A, then Ht2 = dinv * (norm(A) @ W2) ----------

__global__ void __launch_bounds__(256) mm2_kernel(
    const ushort* __restrict__ A2, const ushort* __restrict__ wsw,
    const float* __restrict__ sums, const float* __restrict__ gn_w,
    const float* __restrict__ gn_b, const float* __restrict__ gn_ms,
    const float* __restrict__ ln_w, const float* __restrict__ ln_b,
    const float* __restrict__ dinv, ushort* __restrict__ Ht, int N) {
    __shared__ float sg[64], tg[64], lwv[64], lbv[64];
    int t = threadIdx.x;
    if (t < 64) {
        float invN = 1.0f / (float)N;
        float mean = sums[t] * invN;
        float m2 = sums[64 + t] * invN;
        float ms = gn_ms[t];
        float var = m2 - 2.f * ms * mean * mean + ms * ms * mean * mean;
        float s = gn_w[t] * rsqrtf(var + EPSV);
        sg[t] = s;
        tg[t] = gn_b[t] - s * ms * mean;
        lwv[t] = ln_w[t];
        lbv[t] = ln_b[t];
    }
    __syncthreads();

    int w = t >> 6, lane = t & 63;
    int m = lane & 15, q = lane >> 4;
    int row = blockIdx.x * 64 + w * 16 + m;

    float g[16];
#pragma unroll
    for (int kk = 0; kk < 2; kk++) {
        uint4 u = make_uint4(0, 0, 0, 0);
        if (row < N)
            u = *reinterpret_cast<const uint4*>(A2 + (size_t)row * 64 + kk * 32 + q * 8);
        unsigned uu[4] = {u.x, u.y, u.z, u.w};
#pragma unroll
        for (int p = 0; p < 4; p++) {
            int f0 = kk * 32 + q * 8 + 2 * p;
            g[kk * 8 + 2 * p] = sg[f0] * bf2f((ushort)uu[p]) + tg[f0];
            g[kk * 8 + 2 * p + 1] = sg[f0 + 1] * bf2f((ushort)(uu[p] >> 16)) + tg[f0 + 1];
        }
    }
    float s1 = 0.f;
#pragma unroll
    for (int i = 0; i < 16; i++) s1 += g[i];
    s1 += __shfl_xor(s1, 16);
    s1 += __shfl_xor(s1, 32);
    float mu = s1 * (1.f / 64.f);
    float s2 = 0.f;
#pragma unroll
    for (int i = 0; i < 16; i++) {
        float c = g[i] - mu;
        s2 += c * c;
    }
    s2 += __shfl_xor(s2, 16);
    s2 += __shfl_xor(s2, 32);
    float rs = rsqrtf(s2 * (1.f / 64.f) + EPSV);

    bf16x8 afrag[2];
#pragma unroll
    for (int kk = 0; kk < 2; kk++) {
#pragma unroll
        for (int j = 0; j < 8; j++) {
            int f = kk * 32 + q * 8 + j;
            float y = lwv[f] * (g[kk * 8 + j] - mu) * rs + lbv[f];
            afrag[kk][j] = (short)f2bf(y);
        }
    }

    float dv[4];
#pragma unroll
    for (int reg = 0; reg < 4; reg++) {
        int r = blockIdx.x * 64 + w * 16 + q * 4 + reg;
        dv[reg] = (r < N) ? dinv[r] : 0.f;
    }

    const bf16x8* wp = reinterpret_cast<const bf16x8*>(wsw);
#pragma unroll
    for (int ct = 0; ct < 4; ct++) {
        f32x4 acc = {0.f, 0.f, 0.f, 0.f};
#pragma unroll
        for (int kk = 0; kk < 2; kk++) {
            bf16x8 b = wp[(kk * 4 + q) * 64 + ct * 16 + m];
            acc = __builtin_amdgcn_mfma_f32_16x16x32_bf16(afrag[kk], b, acc, 0, 0, 0);
        }
#pragma unroll
        for (int reg = 0; reg < 4; reg++) {
            int r = blockIdx.x * 64 + w * 16 + q * 4 + reg;
            if (r < N) Ht[(size_t)r * 64 + ct * 16 + m] = f2bf(acc[reg] * dv[reg]);
        }
    }
}

// ---------- edge aggregation v4: 2 nodes/wave interleaved, 8 loads in flight ----------
// wave handles nodes (2j, 2j+1); srcs holds src*16 (uint2 row offset); lane = g*16+fq.
// All shfls converged (uniform loops); lanes >= bn hold ZROW so no post-shfl clamp.
// Zero row lives at Ht[N] (ZROW = N*16).

__global__ void __launch_bounds__(256) agg_kernel(
    const ushort* __restrict__ Ht, const int* __restrict__ rp, const int* __restrict__ srcs,
    const float* __restrict__ dinv, const float* __restrict__ bias,
    ushort* __restrict__ out, float* __restrict__ sums, int N) {
    int wid = (blockIdx.x * blockDim.x + threadIdx.x) >> 6;
    int nw = (gridDim.x * blockDim.x) >> 6;
    int lane = threadIdx.x & 63;
    int g = lane >> 4, fq = lane & 15;
    const int ZROW = N * 16;
    const uint2* H2 = reinterpret_cast<const uint2*>(Ht);
    uint2* O2 = reinterpret_cast<uint2*>(out);
    float bb0 = bias[4 * fq], bb1 = bias[4 * fq + 1], bb2 = bias[4 * fq + 2],
          bb3 = bias[4 * fq + 3];
    float ps1[4] = {0, 0, 0, 0}, ps2[4] = {0, 0, 0, 0};

    for (int j = wid; 2 * j < N; j += nw) {
        int iA = 2 * j, iB = iA + 1;
        int begA = rp[iA], mid = rp[iA + 1];
        int endB = (iB < N) ? rp[iB + 1] : mid;
        int degA = mid - begA, degB = endB - mid;
        float aA0 = 0.f, aA1 = 0.f, aA2 = 0.f, aA3 = 0.f;
        float aB0 = 0.f, aB1 = 0.f, aB2 = 0.f, aB3 = 0.f;
        int bA = 0, bB = 0;
        while (bA < degA || bB < degB) {
            int bnA = degA - bA; bnA = bnA > 64 ? 64 : bnA;
            int bnB = degB - bB; bnB = bnB > 64 ? 64 : bnB;
            int svA = (lane < bnA) ? srcs[begA + bA + lane] : ZROW;
            int svB = (lane < bnB) ? srcs[mid + bB + lane] : ZROW;
            int cn = bnA > bnB ? bnA : bnB;
            for (int kb = 0; kb < cn; kb += 16) {
                int e = kb + g;
                int sA0 = __shfl(svA, e),      sA1 = __shfl(svA, e + 4);
                int sA2 = __shfl(svA, e + 8),  sA3 = __shfl(svA, e + 12);
                int sB0 = __shfl(svB, e),      sB1 = __shfl(svB, e + 4);
                int sB2 = __shfl(svB, e + 8),  sB3 = __shfl(svB, e + 12);
                uint2 uA0 = H2[sA0 + fq], uA1 = H2[sA1 + fq];
                uint2 uA2 = H2[sA2 + fq], uA3 = H2[sA3 + fq];
                uint2 uB0 = H2[sB0 + fq], uB1 = H2[sB1 + fq];
                uint2 uB2 = H2[sB2 + fq], uB3 = H2[sB3 + fq];
                acc2(aA0, aA1, uA0.x); acc2(aA2, aA3, uA0.y);
                acc2(aA0, aA1, uA1.x); acc2(aA2, aA3, uA1.y);
                acc2(aA0, aA1, uA2.x); acc2(aA2, aA3, uA2.y);
                acc2(aA0, aA1, uA3.x); acc2(aA2, aA3, uA3.y);
                acc2(aB0, aB1, uB0.x); acc2(aB2, aB3, uB0.y);
                acc2(aB0, aB1, uB1.x); acc2(aB2, aB3, uB1.y);
                acc2(aB0, aB1, uB2.x); acc2(aB2, aB3, uB2.y);
                acc2(aB0, aB1, uB3.x); acc2(aB2, aB3, uB3.y);
            }
            bA += (bnA > 0 ? bnA : 0);
            bB += (bnB > 0 ? bnB : 0);
        }
        aA0 += __shfl_xor(aA0, 16); aA0 += __shfl_xor(aA0, 32);
        aA1 += __shfl_xor(aA1, 16); aA1 += __shfl_xor(aA1, 32);
        aA2 += __shfl_xor(aA2, 16); aA2 += __shfl_xor(aA2, 32);
        aA3 += __shfl_xor(aA3, 16); aA3 += __shfl_xor(aA3, 32);
        aB0 += __shfl_xor(aB0, 16); aB0 += __shfl_xor(aB0, 32);
        aB1 += __shfl_xor(aB1, 16); aB1 += __shfl_xor(aB1, 32);
        aB2 += __shfl_xor(aB2, 16); aB2 += __shfl_xor(aB2, 32);
        aB3 += __shfl_xor(aB3, 16); aB3 += __shfl_xor(aB3, 32);

        float diA = dinv[iA];
        float diB = (iB < N) ? dinv[iB] : 0.f;
        uint2 usA = H2[(size_t)iA * 16 + fq];
        uint2 usB = H2[(size_t)((iB < N) ? iB * 16 : ZROW) + fq];
        float vA0 = fmaxf(diA * aA0 + diA * bf2f((ushort)usA.x) + bb0, 0.f);
        float vA1 = fmaxf(diA * aA1 + diA * bf2f((ushort)(usA.x >> 16)) + bb1, 0.f);
        float vA2 = fmaxf(diA * aA2 + diA * bf2f((ushort)usA.y) + bb2, 0.f);
        float vA3 = fmaxf(diA * aA3 + diA * bf2f((ushort)(usA.y >> 16)) + bb3, 0.f);
        float vB0 = fmaxf(diB * aB0 + diB * bf2f((ushort)usB.x) + bb0, 0.f);
        float vB1 = fmaxf(diB * aB1 + diB * bf2f((ushort)(usB.x >> 16)) + bb1, 0.f);
        float vB2 = fmaxf(diB * aB2 + diB * bf2f((ushort)usB.y) + bb2, 0.f);
        float vB3 = fmaxf(diB * aB3 + diB * bf2f((ushort)(usB.y >> 16)) + bb3, 0.f);
        if (g == 0) {
            uint2 o;
            o.x = (unsigned)f2bf(vA0) | ((unsigned)f2bf(vA1) << 16);
            o.y = (unsigned)f2bf(vA2) | ((unsigned)f2bf(vA3) << 16);
            O2[(size_t)iA * 16 + fq] = o;
            ps1[0] += vA0; ps1[1] += vA1; ps1[2] += vA2; ps1[3] += vA3;
            ps2[0] += vA0 * vA0; ps2[1] += vA1 * vA1;
            ps2[2] += vA2 * vA2; ps2[3] += vA3 * vA3;
            if (iB < N) {
                ps1[0] += vB0; ps1[1] += vB1; ps1[2] += vB2; ps1[3] += vB3;
                ps2[0] += vB0 * vB0; ps2[1] += vB1 * vB1;
                ps2[2] += vB2 * vB2; ps2[3] += vB3 * vB3;
            }
        }
        if (g == 1 && iB < N) {
            uint2 o;
            o.x = (unsigned)f2bf(vB0) | ((unsigned)f2bf(vB1) << 16);
            o.y = (unsigned)f2bf(vB2) | ((unsigned)f2bf(vB3) << 16);
            O2[(size_t)iB * 16 + fq] = o;
        }
    }

    __shared__ float red[4][16][8];
    int wv = threadIdx.x >> 6;
    if (g == 0) {
#pragma unroll
        for (int p = 0; p < 4; p++) {
            red[wv][fq][p] = ps1[p];
            red[wv][fq][4 + p] = ps2[p];
        }
    }
    __syncthreads();
    if (threadIdx.x < 128) {
        int fqq = threadIdx.x >> 3, c = threadIdx.x & 7;
        float v = red[0][fqq][c] + red[1][fqq][c] + red[2][fqq][c] + red[3][fqq][c];
        atomicAdd(&sums[(c >> 2) * 64 + fqq * 4 + (c & 3)], v);
    }
}

// ---------- layer-2 norms + max-pool ----------

__device__ __forceinline__ float gn_ln_row(float x, float mean, float var, float ms, float gw,
                                           float gb, float lw, float lb) {
    float g = gw * (x - ms * mean) * rsqrtf(var + EPSV) + gb;
    float mu = g;
#pragma unroll
    for (int off = 32; off; off >>= 1) mu += __shfl_xor(mu, off);
    mu *= (1.f / 64.f);
    float c = g - mu;
    float vv = c * c;
#pragma unroll
    for (int off = 32; off; off >>= 1) vv += __shfl_xor(vv, off);
    vv *= (1.f / 64.f);
    return lw * c * rsqrtf(vv + EPSV) + lb;
}

__device__ __forceinline__ unsigned fkey(float f) {
    unsigned u = __float_as_uint(f);
    return (u & 0x80000000u) ? ~u : (u | 0x80000000u);
}

__global__ void gnlnmax_kernel(const ushort* __restrict__ A, const float* __restrict__ sums,
                               const float* __restrict__ gn_w, const float* __restrict__ gn_b,
                               const float* __restrict__ gn_ms, const float* __restrict__ ln_w,
                               const float* __restrict__ ln_b, unsigned* __restrict__ pooled,
                               int N) {
    __shared__ float lmax[256];
    int lane = threadIdx.x & 63;
    int wave0 = (blockIdx.x * blockDim.x + threadIdx.x) >> 6;
    int nw = (gridDim.x * blockDim.x) >> 6;
    float invN = 1.0f / (float)N;
    float mean = sums[lane] * invN;
    float m2 = sums[64 + lane] * invN;
    float ms = gn_ms[lane];
    float var = m2 - 2.f * ms * mean * mean + ms * ms * mean * mean;
    float gw = gn_w[lane], gb = gn_b[lane], lw = ln_w[lane], lb = ln_b[lane];
    float mx = -3.4e38f;
    for (int i = wave0; i < N; i += nw) {
        float y = gn_ln_row(bf2f(A[(size_t)i * 64 + lane]), mean, var, ms, gw, gb, lw, lb);
        mx = fmaxf(mx, y);
    }
    lmax[threadIdx.x] = mx;
    __syncthreads();
    if (threadIdx.x < 64) {
        float m = fmaxf(fmaxf(lmax[threadIdx.x], lmax[threadIdx.x + 64]),
                        fmaxf(lmax[threadIdx.x + 128], lmax[threadIdx.x + 192]));
        atomicMax(&pooled[threadIdx.x], fkey(m));
    }
}

// ---------- final FC ----------

__global__ void final_kernel(const unsigned* __restrict__ pooled, const float* __restrict__ fc_W,
                             const float* __restrict__ fc_b, float* __restrict__ out) {
    __shared__ float p[64];
    int t = threadIdx.x;
    if (t < 64) {
        unsigned u = pooled[t];
        p[t] = (u & 0x80000000u) ? __uint_as_float(u ^ 0x80000000u) : __uint_as_float(~u);
    }
    __syncthreads();
    if (t < 32) {
        float acc = fc_b[t];
#pragma unroll
        for (int f = 0; f < 64; f++) acc += p[f] * fc_W[f * 32 + t];
        out[t] = acc;
    }
}

// ---------- launch ----------

static inline size_t align_up(size_t v, size_t a) { return (v + a - 1) & ~(a - 1); }

extern "C" void kernel_launch(void* const* d_in, const int* in_sizes, int n_in, void* d_out,
                              int out_size, void* d_ws, size_t ws_size, hipStream_t stream) {
    const float* x = (const float*)d_in[0];
    const int* ei = (const int*)d_in[1];
    const float* W1 = (const float*)d_in[2];
    const float* b1 = (const float*)d_in[3];
    const float* W2 = (const float*)d_in[4];
    const float* b2 = (const float*)d_in[5];
    const float* gn_w = (const float*)d_in[6];
    const float* gn_b = (const float*)d_in[7];
    const float* gn_ms = (const float*)d_in[8];
    const float* ln_w = (const float*)d_in[9];
    const float* ln_b = (const float*)d_in[10];
    const float* fc_W = (const float*)d_in[11];
    const float* fc_b = (const float*)d_in[12];
    float* out = (float*)d_out;

    const int N = in_sizes[0] / 128;
    const int E = in_sizes[1] / 2;
    const int NB = (N + CHUNK - 1) / CHUNK;

    char* ws = (char*)d_ws;
    size_t off = 0;
    auto alloc = [&](size_t bytes) {
        char* p = ws + off;
        off = align_up(off + bytes, 256);
        return p;
    };
    int* rp = (int*)alloc((size_t)(N + 1) * 4);
    int* bbase = (int*)alloc((size_t)(NB + 1) * 4);
    int* bcur = (int*)alloc((size_t)(NB + 1) * 4);
    float* dinv = (float*)alloc((size_t)N * 4);
    unsigned* bdata = (unsigned*)alloc((size_t)E * 4);
    int* srcs = (int*)alloc((size_t)E * 4);
    ushort* bufB = (ushort*)alloc((size_t)N * 64 * 2);
    ushort* wsw1 = (ushort*)alloc(128 * 64 * 2);
    ushort* wsw2 = (ushort*)alloc(64 * 64 * 2);
    ushort* bufA = (ushort*)alloc((size_t)N * 64 * 2);  // gather source; zero row follows
    // ---- single contiguous zero-init region: [zrow][bcnt][sums][pooled] ----
    size_t zoff = off;
    ushort* zrow = (ushort*)alloc(128);  // bufA row N (contiguous with bufA)
    int* bcnt = (int*)alloc((size_t)(NB + 1) * 4);
    float* sums = (float*)alloc(256 * 4);
    unsigned* pooled = (unsigned*)alloc(64 * 4);
    size_t zlen = off - zoff;
    (void)zrow;

    hipMemsetAsync(ws + zoff, 0, zlen, stream);

    // CSR build (bucketed)
    int nbB = (E + EPB - 1) / EPB;
    bucket_hist<<<256, 256, 0, stream>>>(ei, bcnt, E, NB);
    bucket_scan<<<1, MAXNB, 0, stream>>>(bcnt, bbase, bcur, rp, NB, N, W1, W2, wsw1, wsw2);
    bucket_scatter<<<nbB, 256, 0, stream>>>(ei, bcur, bdata, E, NB);
    bucket_finish<<<NB, 256, 0, stream>>>(bdata, bbase, rp, dinv, srcs, N);

    int nbMM = (N + 63) / 64;

    // Layer 1
    mm1_kernel<<<nbMM, 256, 0, stream>>>(x, wsw1, dinv, bufA, N);
    agg_kernel<<<2048, 256, 0, stream>>>(bufA, rp, srcs, dinv, b1, bufB, sums, N);

    // Layer 2
    mm2_kernel<<<nbMM, 256, 0, stream>>>(bufB, wsw2, sums, gn_w, gn_b, gn_ms, ln_w, ln_b, dinv,
                                         bufA, N);
    agg_kernel<<<2048, 256, 0, stream>>>(bufA, rp, srcs, dinv, b2, bufB, sums + 128, N);
    gnlnmax_kernel<<<512, 256, 0, stream>>>(bufB, sums + 128, gn_w, gn_b, gn_ms, ln_w, ln_b,
                                            pooled, N);

    final_kernel<<<1, 64, 0, stream>>>(pooled, fc_W, fc_b, out);
}